// Round 2
// baseline (549.471 us; speedup 1.0000x reference)
//
#include <hip/hip_runtime.h>
#include <math.h>

#define MTOT 42000
#define NB 8
#define NCLS 80
#define CAP_LIST 4096
#define CAP_POS 16384
#define MAXT 256
#define NT_MAX 2048

// ---- workspace byte offsets ----
#define O_OVR 0
#define O_GIX (O_OVR + NB*MTOT*4)
#define O_LSC (O_GIX + NB*MTOT*4)
#define O_BCE (O_LSC + NB*MTOT*4)
#define O_BPI (O_BCE + NB*MTOT*4)
#define O_LJ  (O_BPI + NT_MAX*4)
#define O_LST (O_LJ + NT_MAX*4)
#define O_POS (O_LST + NB*MAXT*4)
#define O_BINL (O_POS + CAP_POS*4)
// zeroed region:
#define O_HA  (O_BINL + NB*CAP_LIST*2*4)
#define O_HB  (O_HA + NB*256*4)
#define O_ACC (O_HB + NB*256*4)
#define O_ACCI (O_ACC + 64)
#define O_CNT (O_ACCI + 256)
#define O_ZEND (O_CNT + 64)
// accf: [0]=sum_xy [1]=sum_wh [2]=sum_cls [3]=sum_bce_pos [4]=sum_bce_neg
// acci: [0]=num_pos(list counter) [1]=negsel_cnt [2..9]=ca->bstar16 [10..17]=kres->r [18..25]=tie listn

__device__ __forceinline__ float iou_cxcywh(float acx,float acy,float aw,float ah,
                                            float bcx,float bcy,float bw,float bh){
  float ax0=acx-aw*0.5f, ay0=acy-ah*0.5f, ax1=acx+aw*0.5f, ay1=acy+ah*0.5f;
  float bx0=bcx-bw*0.5f, by0=bcy-bh*0.5f, bx1=bcx+bw*0.5f, by1=bcy+bh*0.5f;
  float tlx=fmaxf(ax0,bx0), tly=fmaxf(ay0,by0);
  float brx=fminf(ax1,bx1), bry=fminf(ay1,by1);
  float wx=fmaxf(brx-tlx,0.f), wy=fmaxf(bry-tly,0.f);
  float inter=wx*wy;
  return inter/(aw*ah+bw*bh-inter+1e-9f);
}

__device__ __forceinline__ float sl1(float x){
  float ax=fabsf(x); return ax<1.f ? 0.5f*ax*ax : ax-0.5f;
}

__device__ __forceinline__ void feat_base(const float* f0,const float* f1,const float* f2,
                                          int i,int m,const float** basep,int* hwp){
  const float* fp; int hw, loc;
  if(m<32000){ fp=f0; hw=6400; loc=m; }
  else if(m<40000){ fp=f1; hw=1600; loc=m-32000; }
  else { fp=f2; hw=400; loc=m-40000; }
  int a=loc/hw, p=loc-a*hw;
  *basep = fp + (size_t)(i*425 + a*85)*(size_t)hw + p;
  *hwp = hw;
}

// parallel per-image target lists: lj[t]=rank within image; cnt[i]=count; list for k_match staging
__global__ void k_prep(const float* __restrict__ tg, int nt, int* __restrict__ list,
                       int* __restrict__ cnt, int* __restrict__ lj){
  int t=blockIdx.x*blockDim.x+threadIdx.x;
  if(t>=nt) return;
  int img=(int)tg[t*6];
  int j=0;
  for(int q=0;q<t;q++) if((int)tg[q*6]==img) j++;
  lj[t]=j;
  if(img>=0 && img<NB){
    atomicAdd(&cnt[img],1);
    if(j<MAXT) list[img*MAXT+j]=t;
  }
}

// per (image, prior): max / argmax IoU over that image's targets (first-index tie-break)
__global__ void k_match(const float* __restrict__ tg, const float* __restrict__ priors,
                        const int* __restrict__ list, const int* __restrict__ cnt,
                        float* __restrict__ ovr, int* __restrict__ gix){
  __shared__ float st[MAXT*6];
  __shared__ int   sidx[MAXT];
  int i = blockIdx.y;
  int n = min(cnt[i],MAXT);
  for(int j=threadIdx.x;j<n;j+=blockDim.x){
    int t=list[i*MAXT+j];
    sidx[j]=t;
    #pragma unroll
    for(int q=0;q<6;q++) st[j*6+q]=tg[t*6+q];
  }
  __syncthreads();
  int m = blockIdx.x*blockDim.x + threadIdx.x;
  if(m>=MTOT) return;
  float4 pr = ((const float4*)priors)[m];
  float maxv=-1.0f; int bi=0;
  for(int j=0;j<n;j++){
    float v=iou_cxcywh(st[j*6+2],st[j*6+3],st[j*6+4],st[j*6+5], pr.x,pr.y,pr.z,pr.w);
    if(v>maxv){ maxv=v; bi=sidx[j]; }
  }
  ovr[i*MTOT+m]=maxv; gix[i*MTOT+m]=bi;
}

// per target: argmax IoU over all priors (first-index tie-break)
__global__ void k_bestprior(const float* __restrict__ tg, const float* __restrict__ priors,
                            int nt, int* __restrict__ bpi){
  int t=blockIdx.x; if(t>=nt) return;
  float acx=tg[t*6+2],acy=tg[t*6+3],aw=tg[t*6+4],ah=tg[t*6+5];
  float bv=-2.f; int bm=0;
  for(int m=threadIdx.x;m<MTOT;m+=blockDim.x){
    float4 pr=((const float4*)priors)[m];
    float v=iou_cxcywh(acx,acy,aw,ah,pr.x,pr.y,pr.z,pr.w);
    if(v>bv){ bv=v; bm=m; }
  }
  __shared__ float sv[256]; __shared__ int sm[256];
  sv[threadIdx.x]=bv; sm[threadIdx.x]=bm;
  __syncthreads();
  for(int s=128;s>0;s>>=1){
    if(threadIdx.x<s){
      if(sv[threadIdx.x+s]>sv[threadIdx.x] ||
         (sv[threadIdx.x+s]==sv[threadIdx.x] && sm[threadIdx.x+s]<sm[threadIdx.x])){
        sv[threadIdx.x]=sv[threadIdx.x+s]; sm[threadIdx.x]=sm[threadIdx.x+s];
      }
    }
    __syncthreads();
  }
  if(threadIdx.x==0) bpi[t]=sm[0];
}

// forced-prior scatter (parallel, last-wins == survivor has no later same-image same-prior target)
__global__ void k_scatter(const float* __restrict__ tg, int nt,
                          const int* __restrict__ bpi, const int* __restrict__ lj,
                          float* __restrict__ ovr){
  int t=blockIdx.x*blockDim.x+threadIdx.x;
  if(t>=nt) return;
  int img=(int)tg[t*6];
  if(img<0||img>=NB) return;
  int myp=bpi[t];
  for(int q=t+1;q<nt;q++)
    if((int)tg[q*6]==img && bpi[q]==myp) return;   // a later target overwrites
  ovr[img*MTOT+myp]=(float)lj[t];
}

// main pass: per (i,m) compute loss_c, bce; LDS coarse (top-8-bit) hist; compact positives
__global__ void k_main(const float* __restrict__ f0,const float* __restrict__ f1,const float* __restrict__ f2,
                       const float* __restrict__ tg,
                       const float* __restrict__ ovr,const int* __restrict__ gix,
                       float* __restrict__ lsc,float* __restrict__ bcearr,
                       unsigned* __restrict__ histA,
                       int* __restrict__ poslist,int* __restrict__ acci){
  __shared__ unsigned h[256];
  h[threadIdx.x]=0;
  __syncthreads();
  int i=blockIdx.y;
  int m=blockIdx.x*blockDim.x+threadIdx.x;
  if(m<MTOT){
    int gid=i*MTOT+m;
    const float* base; int hw;
    feat_base(f0,f1,f2,i,m,&base,&hw);
    float ov=ovr[gid]; int gi=gix[gid];
    float tc = tg[gi*6+1] + 1.0f;
    bool pos = (ov >= 0.5f) && (tc > 0.f);
    float obj = base[(size_t)4*hw];
    float sp = log1pf(expf(-fabsf(obj)));
    float bce = fmaxf(obj,0.f) - (pos?obj:0.f) + sp;
    float lc  = pos ? 0.f : (fmaxf(-obj,0.f)+sp);
    lsc[gid]=lc; bcearr[gid]=bce;
    atomicAdd(&h[__float_as_uint(lc)>>24],1u);
    if(pos){
      int idx=atomicAdd(&acci[0],1);
      if(idx<CAP_POS) poslist[idx]=gid;
    }
  }
  __syncthreads();
  unsigned c=h[threadIdx.x];
  if(c) atomicAdd(&histA[i*256+threadIdx.x],c);
}

// coarse scan: per image find coarse boundary bin + residual count
__global__ void k_scanA(const unsigned* __restrict__ histA, int* __restrict__ acci){
  int i=blockIdx.x;
  __shared__ unsigned a[256];
  a[threadIdx.x]=histA[i*256+threadIdx.x];
  __syncthreads();
  if(threadIdx.x==0){
    int np=acci[0];
    int k=min(np, MTOT-np);
    if(k<=0){ acci[2+i]=0x7fffffff; acci[10+i]=0; return; }
    int run=0;
    for(int c=255;c>=0;c--){
      int cb=(int)a[c];
      if(run<k && run+cb>=k){ acci[2+i]=c; acci[10+i]=k-run; return; }
      run+=cb;
    }
    acci[2+i]=0; acci[10+i]=k-run;  // unreachable (total>=k)
  }
}

// fine hist: elements in coarse boundary bin, on next 8 bits
__global__ void k_histB(const float* __restrict__ lsc, const int* __restrict__ acci,
                        unsigned* __restrict__ histB){
  __shared__ unsigned h[256];
  h[threadIdx.x]=0;
  __syncthreads();
  int i=blockIdx.y;
  int ca=acci[2+i];
  int m=blockIdx.x*blockDim.x+threadIdx.x;
  if(m<MTOT && ca!=0x7fffffff){
    unsigned u=__float_as_uint(lsc[i*MTOT+m]);
    if((int)(u>>24)==ca) atomicAdd(&h[(u>>16)&0xFF],1u);
  }
  __syncthreads();
  unsigned c=h[threadIdx.x];
  if(c) atomicAdd(&histB[i*256+threadIdx.x],c);
}

// fine scan: finalize 16-bit boundary bin + in-bin residual
__global__ void k_scanB(const unsigned* __restrict__ histB, int* __restrict__ acci){
  int i=blockIdx.x;
  __shared__ unsigned a[256];
  a[threadIdx.x]=histB[i*256+threadIdx.x];
  __syncthreads();
  if(threadIdx.x==0){
    int ca=acci[2+i], kres=acci[10+i];
    if(ca==0x7fffffff || kres<=0){ acci[2+i]=0x7fffffff; acci[10+i]=0; return; }
    int run=0;
    for(int f=255;f>=0;f--){
      int cb=(int)a[f];
      if(run<kres && run+cb>=kres){ acci[2+i]=(ca<<8)|f; acci[10+i]=kres-run; return; }
      run+=cb;
    }
    acci[2+i]=(ca<<8); acci[10+i]=kres-run;  // unreachable
  }
}

// select negatives strictly above 16-bit threshold bin; collect boundary-bin members
__global__ void k_select(const float* __restrict__ lsc,const float* __restrict__ bcearr,
                         int* __restrict__ acci,float* __restrict__ accf,
                         int* __restrict__ binlist){
  int gid=blockIdx.x*blockDim.x+threadIdx.x;
  if(gid>=NB*MTOT) return;
  int i=gid/MTOT;
  int bs=acci[2+i];
  unsigned u=__float_as_uint(lsc[gid]);
  int bin=(int)(u>>16);
  if(bin>bs){
    atomicAdd(&accf[4], bcearr[gid]);
    atomicAdd(&acci[1], 1);
  } else if(bin==bs){
    int idx=atomicAdd(&acci[18+i],1);
    if(idx<CAP_LIST){
      binlist[((size_t)i*CAP_LIST+idx)*2  ]=(int)u;
      binlist[((size_t)i*CAP_LIST+idx)*2+1]=gid;
    }
  }
}

// stable tie-resolution inside the boundary bin (value desc, index asc)
__global__ void k_ties(const float* __restrict__ bcearr,int* __restrict__ acci,
                       float* __restrict__ accf,const int* __restrict__ binlist){
  int i=blockIdx.x;
  if(acci[2+i]==0x7fffffff) return;
  int n=min(acci[18+i],CAP_LIST);
  int r=acci[10+i];
  for(int e=threadIdx.x;e<n;e+=blockDim.x){
    unsigned ue=(unsigned)binlist[((size_t)i*CAP_LIST+e)*2];
    int ge=binlist[((size_t)i*CAP_LIST+e)*2+1];
    int rank=0;
    for(int q=0;q<n;q++){
      unsigned uq=(unsigned)binlist[((size_t)i*CAP_LIST+q)*2];
      int gq=binlist[((size_t)i*CAP_LIST+q)*2+1];
      rank += ((uq>ue) || (uq==ue && gq<ge)) ? 1 : 0;
    }
    if(rank<r){
      atomicAdd(&accf[4], bcearr[ge]);
      atomicAdd(&acci[1], 1);
    }
  }
}

// one wave per positive: parallel 80-class softmax + box loss + bce_pos
__global__ void k_pos(const float* __restrict__ f0,const float* __restrict__ f1,const float* __restrict__ f2,
                      const float* __restrict__ tg,const float* __restrict__ priors,
                      const int* __restrict__ gix,const int* __restrict__ poslist,
                      const float* __restrict__ bcearr,
                      float* __restrict__ accf,const int* __restrict__ acci){
  int np=min(acci[0],CAP_POS);
  int w=(blockIdx.x*blockDim.x+threadIdx.x)>>6;
  int lane=threadIdx.x&63;
  int nw=(gridDim.x*blockDim.x)>>6;
  for(int p=w;p<np;p+=nw){
    int gid=poslist[p];
    int i=gid/MTOT, m=gid-i*MTOT;
    const float* base; int hw;
    feat_base(f0,f1,f2,i,m,&base,&hw);
    int gi=gix[gid];
    float tc=tg[gi*6+1]+1.f;
    int label=min(NCLS-1,max(0,(int)tc-1));
    float v0=base[(size_t)(5+lane)*hw];
    float v1=(lane<16)? base[(size_t)(69+lane)*hw] : -3.0e38f;
    float mx=fmaxf(v0,v1);
    #pragma unroll
    for(int o=32;o>0;o>>=1) mx=fmaxf(mx,__shfl_xor(mx,o));
    float se=expf(v0-mx)+((lane<16)?expf(v1-mx):0.f);
    float xl=((lane==label)?v0:0.f)+((lane<16&&lane+64==label)?v1:0.f);
    #pragma unroll
    for(int o=32;o>0;o>>=1){ se+=__shfl_xor(se,o); xl+=__shfl_xor(xl,o); }
    if(lane==0){
      float ce=logf(se)+mx-xl;
      float4 pr=((const float4*)priors)[m];
      float bx=tg[gi*6+2],by=tg[gi*6+3],bw=tg[gi*6+4],bh=tg[gi*6+5];
      float tx=(bx-pr.x)/pr.z, ty=(by-pr.y)/pr.w;
      float tw=logf(bw/pr.z), th=logf(bh/pr.w);
      float lxy=sl1(base[0]-tx)+sl1(base[(size_t)hw]-ty);
      float lwh=sl1(base[(size_t)2*hw]-tw)+sl1(base[(size_t)3*hw]-th);
      atomicAdd(&accf[0],lxy);
      atomicAdd(&accf[1],lwh);
      atomicAdd(&accf[2],ce);
      atomicAdd(&accf[3],bcearr[gid]);
    }
  }
}

__global__ void k_final(const float* __restrict__ accf,const int* __restrict__ acci,
                        float* __restrict__ out){
  if(threadIdx.x||blockIdx.x) return;
  int np=acci[0];
  float npf=(float)np;
  float den2=fmaxf(2.f*npf,1.f);
  float lbox=accf[0]/den2 + accf[1]/den2;
  float lcls=accf[2]/fmaxf(npf,1.f);
  float selc=(float)(np+acci[1]);
  float lobj=(accf[3]+accf[4])/fmaxf(selc,1.f);
  out[0]=lbox+lcls+lobj;
  out[1]=lbox;
  out[2]=lobj;
  out[3]=lcls;
}

extern "C" void kernel_launch(void* const* d_in, const int* in_sizes, int n_in,
                              void* d_out, int out_size, void* d_ws, size_t ws_size,
                              hipStream_t stream) {
  const float* f0=(const float*)d_in[0];
  const float* f1=(const float*)d_in[1];
  const float* f2=(const float*)d_in[2];
  const float* tg=(const float*)d_in[3];
  const float* priors=(const float*)d_in[4];
  int nt = in_sizes[3]/6;
  if(nt>NT_MAX) nt=NT_MAX;

  char* ws=(char*)d_ws;
  float*    ovr    =(float*)   (ws+O_OVR);
  int*      gix    =(int*)     (ws+O_GIX);
  float*    lsc    =(float*)   (ws+O_LSC);
  float*    bcearr =(float*)   (ws+O_BCE);
  int*      bpi    =(int*)     (ws+O_BPI);
  int*      lj     =(int*)     (ws+O_LJ);
  int*      list   =(int*)     (ws+O_LST);
  int*      poslist=(int*)     (ws+O_POS);
  int*      binlist=(int*)     (ws+O_BINL);
  unsigned* histA  =(unsigned*)(ws+O_HA);
  unsigned* histB  =(unsigned*)(ws+O_HB);
  float*    accf   =(float*)   (ws+O_ACC);
  int*      acci   =(int*)     (ws+O_ACCI);
  int*      cnt    =(int*)     (ws+O_CNT);

  // zero hists + accumulators + counters (every call; graph replays must be deterministic)
  hipMemsetAsync(ws+O_HA, 0, (size_t)(O_ZEND-O_HA), stream);

  int ntb=(nt+255)/256;
  k_prep<<<ntb,256,0,stream>>>(tg,nt,list,cnt,lj);
  dim3 gm((MTOT+255)/256, NB);
  k_match<<<gm,256,0,stream>>>(tg,priors,list,cnt,ovr,gix);
  k_bestprior<<<nt,256,0,stream>>>(tg,priors,nt,bpi);
  k_scatter<<<ntb,256,0,stream>>>(tg,nt,bpi,lj,ovr);
  k_main<<<gm,256,0,stream>>>(f0,f1,f2,tg,ovr,gix,lsc,bcearr,histA,poslist,acci);
  k_scanA<<<NB,256,0,stream>>>(histA,acci);
  k_histB<<<gm,256,0,stream>>>(lsc,acci,histB);
  k_scanB<<<NB,256,0,stream>>>(histB,acci);
  int tot=NB*MTOT, blocks=(tot+255)/256;
  k_select<<<blocks,256,0,stream>>>(lsc,bcearr,acci,accf,binlist);
  k_ties<<<NB,256,0,stream>>>(bcearr,acci,accf,binlist);
  k_pos<<<64,256,0,stream>>>(f0,f1,f2,tg,priors,gix,poslist,bcearr,accf,acci);
  k_final<<<1,1,0,stream>>>(accf,acci,(float*)d_out);
}

// Round 5
// 545.663 us; speedup vs baseline: 1.0070x; 1.0070x over previous
//
#include <hip/hip_runtime.h>
#include <math.h>

#define MTOT 42000
#define NB 8
#define NCLS 80
#define CAP_LIST 4096
#define CAP_POS 16384
#define MAXT 256
#define NT_MAX 2048

// ---- workspace byte offsets ----
#define O_OVR 0
#define O_GIX (O_OVR + NB*MTOT*4)
#define O_LSC (O_GIX + NB*MTOT*4)
#define O_BCE (O_LSC + NB*MTOT*4)
#define O_BPI (O_BCE + NB*MTOT*4)
#define O_LJ  (O_BPI + NT_MAX*4)
#define O_LST (O_LJ + NT_MAX*4)
#define O_POS (O_LST + NB*MAXT*4)
#define O_BINL (O_POS + CAP_POS*4)
// zeroed region:
#define O_HA  (O_BINL + NB*CAP_LIST*2*4)
#define O_HB  (O_HA + NB*256*4)
#define O_ACC (O_HB + NB*256*4)
#define O_ACCI (O_ACC + 64)
#define O_CNT (O_ACCI + 256)
#define O_ZEND (O_CNT + 64)
// accf: [0]=sum_xy [1]=sum_wh [2]=sum_cls [3]=sum_bce_pos [4]=sum_bce_neg
// acci: [0]=num_pos(list counter) [1]=negsel_cnt [2..9]=ca->bstar16 [10..17]=kres->r [18..25]=tie listn

__device__ __forceinline__ float iou_cxcywh(float acx,float acy,float aw,float ah,
                                            float bcx,float bcy,float bw,float bh){
  float ax0=acx-aw*0.5f, ay0=acy-ah*0.5f, ax1=acx+aw*0.5f, ay1=acy+ah*0.5f;
  float bx0=bcx-bw*0.5f, by0=bcy-bh*0.5f, bx1=bcx+bw*0.5f, by1=bcy+bh*0.5f;
  float tlx=fmaxf(ax0,bx0), tly=fmaxf(ay0,by0);
  float brx=fminf(ax1,bx1), bry=fminf(ay1,by1);
  float wx=fmaxf(brx-tlx,0.f), wy=fmaxf(bry-tly,0.f);
  float inter=wx*wy;
  return inter/(aw*ah+bw*bh-inter+1e-9f);
}

__device__ __forceinline__ float sl1(float x){
  float ax=fabsf(x); return ax<1.f ? 0.5f*ax*ax : ax-0.5f;
}

__device__ __forceinline__ void feat_base(const float* f0,const float* f1,const float* f2,
                                          int i,int m,const float** basep,int* hwp){
  const float* fp; int hw, loc;
  if(m<32000){ fp=f0; hw=6400; loc=m; }
  else if(m<40000){ fp=f1; hw=1600; loc=m-32000; }
  else { fp=f2; hw=400; loc=m-40000; }
  int a=loc/hw, p=loc-a*hw;
  *basep = fp + (size_t)(i*425 + a*85)*(size_t)hw + p;
  *hwp = hw;
}

// parallel per-image target lists: lj[t]=rank within image; cnt[i]=count; list for k_match staging
__global__ void k_prep(const float* __restrict__ tg, int nt, int* __restrict__ list,
                       int* __restrict__ cnt, int* __restrict__ lj){
  int t=blockIdx.x*blockDim.x+threadIdx.x;
  if(t>=nt) return;
  int img=(int)tg[t*6];
  int j=0;
  for(int q=0;q<t;q++) if((int)tg[q*6]==img) j++;
  lj[t]=j;
  if(img>=0 && img<NB){
    atomicAdd(&cnt[img],1);
    if(j<MAXT) list[img*MAXT+j]=t;
  }
}

// per (image, prior): max / argmax IoU over that image's targets (first-index tie-break)
__global__ void k_match(const float* __restrict__ tg, const float* __restrict__ priors,
                        const int* __restrict__ list, const int* __restrict__ cnt,
                        float* __restrict__ ovr, int* __restrict__ gix){
  __shared__ float st[MAXT*6];
  __shared__ int   sidx[MAXT];
  int i = blockIdx.y;
  int n = min(cnt[i],MAXT);
  for(int j=threadIdx.x;j<n;j+=blockDim.x){
    int t=list[i*MAXT+j];
    sidx[j]=t;
    #pragma unroll
    for(int q=0;q<6;q++) st[j*6+q]=tg[t*6+q];
  }
  __syncthreads();
  int m = blockIdx.x*blockDim.x + threadIdx.x;
  if(m>=MTOT) return;
  float4 pr = ((const float4*)priors)[m];
  float maxv=-1.0f; int bi=0;
  for(int j=0;j<n;j++){
    float v=iou_cxcywh(st[j*6+2],st[j*6+3],st[j*6+4],st[j*6+5], pr.x,pr.y,pr.z,pr.w);
    if(v>maxv){ maxv=v; bi=sidx[j]; }
  }
  ovr[i*MTOT+m]=maxv; gix[i*MTOT+m]=bi;
}

// per target: argmax IoU over all priors (first-index tie-break)
__global__ void k_bestprior(const float* __restrict__ tg, const float* __restrict__ priors,
                            int nt, int* __restrict__ bpi){
  int t=blockIdx.x; if(t>=nt) return;
  float acx=tg[t*6+2],acy=tg[t*6+3],aw=tg[t*6+4],ah=tg[t*6+5];
  float bv=-2.f; int bm=0;
  for(int m=threadIdx.x;m<MTOT;m+=blockDim.x){
    float4 pr=((const float4*)priors)[m];
    float v=iou_cxcywh(acx,acy,aw,ah,pr.x,pr.y,pr.z,pr.w);
    if(v>bv){ bv=v; bm=m; }
  }
  __shared__ float sv[256]; __shared__ int sm[256];
  sv[threadIdx.x]=bv; sm[threadIdx.x]=bm;
  __syncthreads();
  for(int s=128;s>0;s>>=1){
    if(threadIdx.x<s){
      if(sv[threadIdx.x+s]>sv[threadIdx.x] ||
         (sv[threadIdx.x+s]==sv[threadIdx.x] && sm[threadIdx.x+s]<sm[threadIdx.x])){
        sv[threadIdx.x]=sv[threadIdx.x+s]; sm[threadIdx.x]=sm[threadIdx.x+s];
      }
    }
    __syncthreads();
  }
  if(threadIdx.x==0) bpi[t]=sm[0];
}

// forced-prior scatter (parallel, last-wins == survivor has no later same-image same-prior target)
__global__ void k_scatter(const float* __restrict__ tg, int nt,
                          const int* __restrict__ bpi, const int* __restrict__ lj,
                          float* __restrict__ ovr){
  int t=blockIdx.x*blockDim.x+threadIdx.x;
  if(t>=nt) return;
  int img=(int)tg[t*6];
  if(img<0||img>=NB) return;
  int myp=bpi[t];
  for(int q=t+1;q<nt;q++)
    if((int)tg[q*6]==img && bpi[q]==myp) return;   // a later target overwrites
  ovr[img*MTOT+myp]=(float)lj[t];
}

// main pass: per (i,m) compute loss_c, bce; LDS coarse (top-8-bit) hist; compact positives
__global__ void k_main(const float* __restrict__ f0,const float* __restrict__ f1,const float* __restrict__ f2,
                       const float* __restrict__ tg,
                       const float* __restrict__ ovr,const int* __restrict__ gix,
                       float* __restrict__ lsc,float* __restrict__ bcearr,
                       unsigned* __restrict__ histA,
                       int* __restrict__ poslist,int* __restrict__ acci){
  __shared__ unsigned h[256];
  h[threadIdx.x]=0;
  __syncthreads();
  int i=blockIdx.y;
  int m=blockIdx.x*blockDim.x+threadIdx.x;
  if(m<MTOT){
    int gid=i*MTOT+m;
    const float* base; int hw;
    feat_base(f0,f1,f2,i,m,&base,&hw);
    float ov=ovr[gid]; int gi=gix[gid];
    float tc = tg[gi*6+1] + 1.0f;
    bool pos = (ov >= 0.5f) && (tc > 0.f);
    float obj = base[(size_t)4*hw];
    float sp = log1pf(expf(-fabsf(obj)));
    float bce = fmaxf(obj,0.f) - (pos?obj:0.f) + sp;
    float lc  = pos ? 0.f : (fmaxf(-obj,0.f)+sp);
    lsc[gid]=lc; bcearr[gid]=bce;
    atomicAdd(&h[__float_as_uint(lc)>>24],1u);
    if(pos){
      int idx=atomicAdd(&acci[0],1);
      if(idx<CAP_POS) poslist[idx]=gid;
    }
  }
  __syncthreads();
  unsigned c=h[threadIdx.x];
  if(c) atomicAdd(&histA[i*256+threadIdx.x],c);
}

// coarse scan: per image find coarse boundary bin + residual count
__global__ void k_scanA(const unsigned* __restrict__ histA, int* __restrict__ acci){
  int i=blockIdx.x;
  __shared__ unsigned a[256];
  a[threadIdx.x]=histA[i*256+threadIdx.x];
  __syncthreads();
  if(threadIdx.x==0){
    int np=acci[0];
    int k=min(np, MTOT-np);
    if(k<=0){ acci[2+i]=0x7fffffff; acci[10+i]=0; return; }
    int run=0;
    for(int c=255;c>=0;c--){
      int cb=(int)a[c];
      if(run<k && run+cb>=k){ acci[2+i]=c; acci[10+i]=k-run; return; }
      run+=cb;
    }
    acci[2+i]=0; acci[10+i]=k-run;  // unreachable (total>=k)
  }
}

// fine hist: elements in coarse boundary bin, on next 8 bits
__global__ void k_histB(const float* __restrict__ lsc, const int* __restrict__ acci,
                        unsigned* __restrict__ histB){
  __shared__ unsigned h[256];
  h[threadIdx.x]=0;
  __syncthreads();
  int i=blockIdx.y;
  int ca=acci[2+i];
  int m=blockIdx.x*blockDim.x+threadIdx.x;
  if(m<MTOT && ca!=0x7fffffff){
    unsigned u=__float_as_uint(lsc[i*MTOT+m]);
    if((int)(u>>24)==ca) atomicAdd(&h[(u>>16)&0xFF],1u);
  }
  __syncthreads();
  unsigned c=h[threadIdx.x];
  if(c) atomicAdd(&histB[i*256+threadIdx.x],c);
}

// fine scan: finalize 16-bit boundary bin + in-bin residual
__global__ void k_scanB(const unsigned* __restrict__ histB, int* __restrict__ acci){
  int i=blockIdx.x;
  __shared__ unsigned a[256];
  a[threadIdx.x]=histB[i*256+threadIdx.x];
  __syncthreads();
  if(threadIdx.x==0){
    int ca=acci[2+i], kres=acci[10+i];
    if(ca==0x7fffffff || kres<=0){ acci[2+i]=0x7fffffff; acci[10+i]=0; return; }
    int run=0;
    for(int f=255;f>=0;f--){
      int cb=(int)a[f];
      if(run<kres && run+cb>=kres){ acci[2+i]=(ca<<8)|f; acci[10+i]=kres-run; return; }
      run+=cb;
    }
    acci[2+i]=(ca<<8); acci[10+i]=kres-run;  // unreachable
  }
}

// select negatives strictly above 16-bit threshold bin; collect boundary-bin members
__global__ void k_select(const float* __restrict__ lsc,const float* __restrict__ bcearr,
                         int* __restrict__ acci,float* __restrict__ accf,
                         int* __restrict__ binlist){
  int gid=blockIdx.x*blockDim.x+threadIdx.x;
  if(gid>=NB*MTOT) return;
  int i=gid/MTOT;
  int bs=acci[2+i];
  unsigned u=__float_as_uint(lsc[gid]);
  int bin=(int)(u>>16);
  if(bin>bs){
    atomicAdd(&accf[4], bcearr[gid]);
    atomicAdd(&acci[1], 1);
  } else if(bin==bs){
    int idx=atomicAdd(&acci[18+i],1);
    if(idx<CAP_LIST){
      binlist[((size_t)i*CAP_LIST+idx)*2  ]=(int)u;
      binlist[((size_t)i*CAP_LIST+idx)*2+1]=gid;
    }
  }
}

// stable tie-resolution inside the boundary bin (value desc, index asc)
__global__ void k_ties(const float* __restrict__ bcearr,int* __restrict__ acci,
                       float* __restrict__ accf,const int* __restrict__ binlist){
  int i=blockIdx.x;
  if(acci[2+i]==0x7fffffff) return;
  int n=min(acci[18+i],CAP_LIST);
  int r=acci[10+i];
  for(int e=threadIdx.x;e<n;e+=blockDim.x){
    unsigned ue=(unsigned)binlist[((size_t)i*CAP_LIST+e)*2];
    int ge=binlist[((size_t)i*CAP_LIST+e)*2+1];
    int rank=0;
    for(int q=0;q<n;q++){
      unsigned uq=(unsigned)binlist[((size_t)i*CAP_LIST+q)*2];
      int gq=binlist[((size_t)i*CAP_LIST+q)*2+1];
      rank += ((uq>ue) || (uq==ue && gq<ge)) ? 1 : 0;
    }
    if(rank<r){
      atomicAdd(&accf[4], bcearr[ge]);
      atomicAdd(&acci[1], 1);
    }
  }
}

// one wave per positive (grid covers CAP_POS waves => full MLP for the scattered
// class-channel gather; waves past num_pos exit immediately)
__global__ void k_pos(const float* __restrict__ f0,const float* __restrict__ f1,const float* __restrict__ f2,
                      const float* __restrict__ tg,const float* __restrict__ priors,
                      const int* __restrict__ gix,const int* __restrict__ poslist,
                      const float* __restrict__ bcearr,
                      float* __restrict__ accf,const int* __restrict__ acci){
  int np=min(acci[0],CAP_POS);
  int p=(blockIdx.x*blockDim.x+threadIdx.x)>>6;
  if(p>=np) return;
  int lane=threadIdx.x&63;
  int gid=poslist[p];
  int i=gid/MTOT, m=gid-i*MTOT;
  const float* base; int hw;
  feat_base(f0,f1,f2,i,m,&base,&hw);
  int gi=gix[gid];
  float tc=tg[gi*6+1]+1.f;
  int label=min(NCLS-1,max(0,(int)tc-1));
  float v0=base[(size_t)(5+lane)*hw];
  float v1=(lane<16)? base[(size_t)(69+lane)*hw] : -3.0e38f;
  float mx=fmaxf(v0,v1);
  #pragma unroll
  for(int o=32;o>0;o>>=1) mx=fmaxf(mx,__shfl_xor(mx,o));
  float se=expf(v0-mx)+((lane<16)?expf(v1-mx):0.f);
  float xl=((lane==label)?v0:0.f)+((lane<16&&lane+64==label)?v1:0.f);
  #pragma unroll
  for(int o=32;o>0;o>>=1){ se+=__shfl_xor(se,o); xl+=__shfl_xor(xl,o); }
  if(lane==0){
    float ce=logf(se)+mx-xl;
    float4 pr=((const float4*)priors)[m];
    float bx=tg[gi*6+2],by=tg[gi*6+3],bw=tg[gi*6+4],bh=tg[gi*6+5];
    float tx=(bx-pr.x)/pr.z, ty=(by-pr.y)/pr.w;
    float tw=logf(bw/pr.z), th=logf(bh/pr.w);
    float lxy=sl1(base[0]-tx)+sl1(base[(size_t)hw]-ty);
    float lwh=sl1(base[(size_t)2*hw]-tw)+sl1(base[(size_t)3*hw]-th);
    atomicAdd(&accf[0],lxy);
    atomicAdd(&accf[1],lwh);
    atomicAdd(&accf[2],ce);
    atomicAdd(&accf[3],bcearr[gid]);
  }
}

__global__ void k_final(const float* __restrict__ accf,const int* __restrict__ acci,
                        float* __restrict__ out){
  if(threadIdx.x||blockIdx.x) return;
  int np=acci[0];
  float npf=(float)np;
  float den2=fmaxf(2.f*npf,1.f);
  float lbox=accf[0]/den2 + accf[1]/den2;
  float lcls=accf[2]/fmaxf(npf,1.f);
  float selc=(float)(np+acci[1]);
  float lobj=(accf[3]+accf[4])/fmaxf(selc,1.f);
  out[0]=lbox+lcls+lobj;
  out[1]=lbox;
  out[2]=lobj;
  out[3]=lcls;
}

extern "C" void kernel_launch(void* const* d_in, const int* in_sizes, int n_in,
                              void* d_out, int out_size, void* d_ws, size_t ws_size,
                              hipStream_t stream) {
  const float* f0=(const float*)d_in[0];
  const float* f1=(const float*)d_in[1];
  const float* f2=(const float*)d_in[2];
  const float* tg=(const float*)d_in[3];
  const float* priors=(const float*)d_in[4];
  int nt = in_sizes[3]/6;
  if(nt>NT_MAX) nt=NT_MAX;

  char* ws=(char*)d_ws;
  float*    ovr    =(float*)   (ws+O_OVR);
  int*      gix    =(int*)     (ws+O_GIX);
  float*    lsc    =(float*)   (ws+O_LSC);
  float*    bcearr =(float*)   (ws+O_BCE);
  int*      bpi    =(int*)     (ws+O_BPI);
  int*      lj     =(int*)     (ws+O_LJ);
  int*      list   =(int*)     (ws+O_LST);
  int*      poslist=(int*)     (ws+O_POS);
  int*      binlist=(int*)     (ws+O_BINL);
  unsigned* histA  =(unsigned*)(ws+O_HA);
  unsigned* histB  =(unsigned*)(ws+O_HB);
  float*    accf   =(float*)   (ws+O_ACC);
  int*      acci   =(int*)     (ws+O_ACCI);
  int*      cnt    =(int*)     (ws+O_CNT);

  // zero hists + accumulators + counters (every call; graph replays must be deterministic)
  hipMemsetAsync(ws+O_HA, 0, (size_t)(O_ZEND-O_HA), stream);

  int ntb=(nt+255)/256;
  k_prep<<<ntb,256,0,stream>>>(tg,nt,list,cnt,lj);
  dim3 gm((MTOT+255)/256, NB);
  k_match<<<gm,256,0,stream>>>(tg,priors,list,cnt,ovr,gix);
  k_bestprior<<<nt,256,0,stream>>>(tg,priors,nt,bpi);
  k_scatter<<<ntb,256,0,stream>>>(tg,nt,bpi,lj,ovr);
  k_main<<<gm,256,0,stream>>>(f0,f1,f2,tg,ovr,gix,lsc,bcearr,histA,poslist,acci);
  k_scanA<<<NB,256,0,stream>>>(histA,acci);
  k_histB<<<gm,256,0,stream>>>(lsc,acci,histB);
  k_scanB<<<NB,256,0,stream>>>(histB,acci);
  int tot=NB*MTOT, blocks=(tot+255)/256;
  k_select<<<blocks,256,0,stream>>>(lsc,bcearr,acci,accf,binlist);
  k_ties<<<NB,256,0,stream>>>(bcearr,acci,accf,binlist);
  // CAP_POS waves = CAP_POS*64 threads / 256 = 4096 blocks
  k_pos<<<(CAP_POS*64)/256,256,0,stream>>>(f0,f1,f2,tg,priors,gix,poslist,bcearr,accf,acci);
  k_final<<<1,1,0,stream>>>(accf,acci,(float*)d_out);
}

// Round 6
// 183.900 us; speedup vs baseline: 2.9879x; 2.9672x over previous
//
#include <hip/hip_runtime.h>
#include <math.h>

#define MTOT 42000
#define NB 8
#define NCLS 80
#define CAP_LIST 4096
#define MAXT 256
#define NT_MAX 2048
#define GX_MAIN 165                 // ceil(42000/256)
#define NBLK_MAIN (GX_MAIN*NB)      // 1320
#define NBLK_SEL 1313               // ceil(336000/256)

// ---- workspace byte offsets ----
#define O_OVR 0
#define O_GIX (O_OVR + NB*MTOT*4)
#define O_LSC (O_GIX + NB*MTOT*4)
#define O_BCE (O_LSC + NB*MTOT*4)
#define O_BPI (O_BCE + NB*MTOT*4)
#define O_LJ  (O_BPI + NT_MAX*4)
#define O_LST (O_LJ + NT_MAX*4)
#define O_PA  (O_LST + NB*MAXT*4)        // k_main float4 partials [NBLK_MAIN]
#define O_PN  (O_PA + NBLK_MAIN*16)      // k_main int partials [NBLK_MAIN]
#define O_P2  (O_PN + NBLK_MAIN*4)       // k_select float2 partials [NBLK_SEL]
#define O_BINL (O_P2 + NBLK_SEL*8)
// zeroed region:
#define O_HA  (O_BINL + NB*CAP_LIST*2*4)
#define O_HB  (O_HA + NB*256*4)
#define O_ACC (O_HB + NB*256*4)
#define O_ACCI (O_ACC + 64)
#define O_CNT (O_ACCI + 256)
#define O_ZEND (O_CNT + 64)
// accf: [0]=sum_xy [1]=sum_wh [2]=sum_cls [3]=sum_bce_pos [5]=tie bce sum
// acci: [0]=num_pos [1]=tie negsel cnt [2..9]=bstar16 [10..17]=r [18..25]=tie listn

__device__ __forceinline__ float iou_cxcywh(float acx,float acy,float aw,float ah,
                                            float bcx,float bcy,float bw,float bh){
  float ax0=acx-aw*0.5f, ay0=acy-ah*0.5f, ax1=acx+aw*0.5f, ay1=acy+ah*0.5f;
  float bx0=bcx-bw*0.5f, by0=bcy-bh*0.5f, bx1=bcx+bw*0.5f, by1=bcy+bh*0.5f;
  float tlx=fmaxf(ax0,bx0), tly=fmaxf(ay0,by0);
  float brx=fminf(ax1,bx1), bry=fminf(ay1,by1);
  float wx=fmaxf(brx-tlx,0.f), wy=fmaxf(bry-tly,0.f);
  float inter=wx*wy;
  return inter/(aw*ah+bw*bh-inter+1e-9f);
}

__device__ __forceinline__ float sl1(float x){
  float ax=fabsf(x); return ax<1.f ? 0.5f*ax*ax : ax-0.5f;
}

__device__ __forceinline__ void feat_base(const float* f0,const float* f1,const float* f2,
                                          int i,int m,const float** basep,int* hwp){
  const float* fp; int hw, loc;
  if(m<32000){ fp=f0; hw=6400; loc=m; }
  else if(m<40000){ fp=f1; hw=1600; loc=m-32000; }
  else { fp=f2; hw=400; loc=m-40000; }
  int a=loc/hw, p=loc-a*hw;
  *basep = fp + (size_t)(i*425 + a*85)*(size_t)hw + p;
  *hwp = hw;
}

// parallel per-image target lists
__global__ void k_prep(const float* __restrict__ tg, int nt, int* __restrict__ list,
                       int* __restrict__ cnt, int* __restrict__ lj){
  int t=blockIdx.x*blockDim.x+threadIdx.x;
  if(t>=nt) return;
  int img=(int)tg[t*6];
  int j=0;
  for(int q=0;q<t;q++) if((int)tg[q*6]==img) j++;
  lj[t]=j;
  if(img>=0 && img<NB){
    atomicAdd(&cnt[img],1);
    if(j<MAXT) list[img*MAXT+j]=t;
  }
}

// per (image, prior): max / argmax IoU over that image's targets (first-index tie-break)
__global__ void k_match(const float* __restrict__ tg, const float* __restrict__ priors,
                        const int* __restrict__ list, const int* __restrict__ cnt,
                        float* __restrict__ ovr, int* __restrict__ gix){
  __shared__ float st[MAXT*6];
  __shared__ int   sidx[MAXT];
  int i = blockIdx.y;
  int n = min(cnt[i],MAXT);
  for(int j=threadIdx.x;j<n;j+=blockDim.x){
    int t=list[i*MAXT+j];
    sidx[j]=t;
    #pragma unroll
    for(int q=0;q<6;q++) st[j*6+q]=tg[t*6+q];
  }
  __syncthreads();
  int m = blockIdx.x*blockDim.x + threadIdx.x;
  if(m>=MTOT) return;
  float4 pr = ((const float4*)priors)[m];
  float maxv=-1.0f; int bi=0;
  for(int j=0;j<n;j++){
    float v=iou_cxcywh(st[j*6+2],st[j*6+3],st[j*6+4],st[j*6+5], pr.x,pr.y,pr.z,pr.w);
    if(v>maxv){ maxv=v; bi=sidx[j]; }
  }
  ovr[i*MTOT+m]=maxv; gix[i*MTOT+m]=bi;
}

// per target: argmax IoU over all priors (first-index tie-break)
__global__ void k_bestprior(const float* __restrict__ tg, const float* __restrict__ priors,
                            int nt, int* __restrict__ bpi){
  int t=blockIdx.x; if(t>=nt) return;
  float acx=tg[t*6+2],acy=tg[t*6+3],aw=tg[t*6+4],ah=tg[t*6+5];
  float bv=-2.f; int bm=0;
  for(int m=threadIdx.x;m<MTOT;m+=blockDim.x){
    float4 pr=((const float4*)priors)[m];
    float v=iou_cxcywh(acx,acy,aw,ah,pr.x,pr.y,pr.z,pr.w);
    if(v>bv){ bv=v; bm=m; }
  }
  __shared__ float sv[256]; __shared__ int sm[256];
  sv[threadIdx.x]=bv; sm[threadIdx.x]=bm;
  __syncthreads();
  for(int s=128;s>0;s>>=1){
    if(threadIdx.x<s){
      if(sv[threadIdx.x+s]>sv[threadIdx.x] ||
         (sv[threadIdx.x+s]==sv[threadIdx.x] && sm[threadIdx.x+s]<sm[threadIdx.x])){
        sv[threadIdx.x]=sv[threadIdx.x+s]; sm[threadIdx.x]=sm[threadIdx.x+s];
      }
    }
    __syncthreads();
  }
  if(threadIdx.x==0) bpi[t]=sm[0];
}

// forced-prior scatter (parallel last-wins)
__global__ void k_scatter(const float* __restrict__ tg, int nt,
                          const int* __restrict__ bpi, const int* __restrict__ lj,
                          float* __restrict__ ovr){
  int t=blockIdx.x*blockDim.x+threadIdx.x;
  if(t>=nt) return;
  int img=(int)tg[t*6];
  if(img<0||img>=NB) return;
  int myp=bpi[t];
  for(int q=t+1;q<nt;q++)
    if((int)tg[q*6]==img && bpi[q]==myp) return;
  ovr[img*MTOT+myp]=(float)lj[t];
}

// main pass: loss_c/bce + LDS hist + per-thread box losses + wave-cooperative CE.
// Atomic-free accumulation: per-block partials (float4 = xy,wh,ce,bcep; int = npos).
__global__ void k_main(const float* __restrict__ f0,const float* __restrict__ f1,const float* __restrict__ f2,
                       const float* __restrict__ tg,const float* __restrict__ priors,
                       const float* __restrict__ ovr,const int* __restrict__ gix,
                       float* __restrict__ lsc,float* __restrict__ bcearr,
                       unsigned* __restrict__ histA,
                       float4* __restrict__ partA,int* __restrict__ partN){
  __shared__ unsigned h[256];
  __shared__ float sxy[4],swh[4],sbp[4],sce[4];
  __shared__ int snp[4];
  int tid=threadIdx.x;
  h[tid]=0;
  __syncthreads();
  int i=blockIdx.y;
  int m=blockIdx.x*blockDim.x+tid;
  int lane=tid&63, wid=tid>>6;
  bool valid=(m<MTOT);

  float lxy=0.f,lwh=0.f,bcep=0.f; int npos=0; bool pos=false; int gi=0;
  if(valid){
    int gid=i*MTOT+m;
    const float* base; int hw;
    feat_base(f0,f1,f2,i,m,&base,&hw);
    float ov=ovr[gid]; gi=gix[gid];
    float tc=tg[gi*6+1]+1.0f;
    pos=(ov>=0.5f)&&(tc>0.f);
    float obj=base[(size_t)4*hw];
    float sp=log1pf(expf(-fabsf(obj)));
    float bce=fmaxf(obj,0.f)-(pos?obj:0.f)+sp;
    float lc=pos?0.f:(fmaxf(-obj,0.f)+sp);
    lsc[gid]=lc; bcearr[gid]=bce;
    atomicAdd(&h[__float_as_uint(lc)>>24],1u);
    if(pos){
      npos=1; bcep=bce;
      float4 pr=((const float4*)priors)[m];
      float bx=tg[gi*6+2],by=tg[gi*6+3],bw=tg[gi*6+4],bh=tg[gi*6+5];
      float tx=(bx-pr.x)/pr.z, ty=(by-pr.y)/pr.w;
      float tw=logf(bw/pr.z), th=logf(bh/pr.w);
      lxy=sl1(base[0]-tx)+sl1(base[(size_t)hw]-ty);
      lwh=sl1(base[(size_t)2*hw]-tw)+sl1(base[(size_t)3*hw]-th);
    }
  }

  // wave-cooperative CE: for each positive lane s, all 64 lanes gather class channels
  float wce=0.f;
  unsigned long long mask=__ballot(valid&&pos);
  while(mask){
    int s=__ffsll(mask)-1;
    mask&=mask-1;
    int m_s=__shfl(m,s);
    int gi_s=__shfl(gi,s);
    const float* bs; int hws;
    feat_base(f0,f1,f2,i,m_s,&bs,&hws);
    int label=(int)(tg[gi_s*6+1]+1.0f)-1;
    label=min(NCLS-1,max(0,label));
    float v0=bs[(size_t)(5+lane)*hws];
    float v1=(lane<16)?bs[(size_t)(69+lane)*hws]:-3.0e38f;
    float mx=fmaxf(v0,v1);
    #pragma unroll
    for(int o=32;o>0;o>>=1) mx=fmaxf(mx,__shfl_xor(mx,o));
    float se=expf(v0-mx)+((lane<16)?expf(v1-mx):0.f);
    float xl=((lane==label)?v0:0.f)+((lane<16&&lane+64==label)?v1:0.f);
    #pragma unroll
    for(int o=32;o>0;o>>=1){ se+=__shfl_xor(se,o); xl+=__shfl_xor(xl,o); }
    wce+=logf(se)+mx-xl;   // identical on all lanes
  }

  // wave reduce per-thread sums
  #pragma unroll
  for(int o=32;o>0;o>>=1){
    lxy+=__shfl_xor(lxy,o); lwh+=__shfl_xor(lwh,o);
    bcep+=__shfl_xor(bcep,o); npos+=__shfl_xor(npos,o);
  }
  if(lane==0){ sxy[wid]=lxy; swh[wid]=lwh; sbp[wid]=bcep; sce[wid]=wce; snp[wid]=npos; }
  __syncthreads();
  unsigned c=h[tid];
  if(c) atomicAdd(&histA[i*256+tid],c);
  if(tid==0){
    float4 pa;
    pa.x=sxy[0]+sxy[1]+sxy[2]+sxy[3];
    pa.y=swh[0]+swh[1]+swh[2]+swh[3];
    pa.z=sce[0]+sce[1]+sce[2]+sce[3];
    pa.w=sbp[0]+sbp[1]+sbp[2]+sbp[3];
    int bid=blockIdx.y*gridDim.x+blockIdx.x;
    partA[bid]=pa;
    partN[bid]=snp[0]+snp[1]+snp[2]+snp[3];
  }
}

// reduce k_main partials -> accf[0..3], acci[0]
__global__ void k_red(const float4* __restrict__ partA,const int* __restrict__ partN,
                      float* __restrict__ accf,int* __restrict__ acci){
  __shared__ float a0[256],a1[256],a2[256],a3[256]; __shared__ int an[256];
  int t=threadIdx.x;
  float x=0,y=0,z=0,w=0; int n=0;
  for(int b=t;b<NBLK_MAIN;b+=256){
    float4 p=partA[b]; x+=p.x; y+=p.y; z+=p.z; w+=p.w; n+=partN[b];
  }
  a0[t]=x; a1[t]=y; a2[t]=z; a3[t]=w; an[t]=n;
  __syncthreads();
  for(int o=128;o>0;o>>=1){
    if(t<o){ a0[t]+=a0[t+o]; a1[t]+=a1[t+o]; a2[t]+=a2[t+o]; a3[t]+=a3[t+o]; an[t]+=an[t+o]; }
    __syncthreads();
  }
  if(t==0){ accf[0]=a0[0]; accf[1]=a1[0]; accf[2]=a2[0]; accf[3]=a3[0]; acci[0]=an[0]; }
}

// coarse scan
__global__ void k_scanA(const unsigned* __restrict__ histA, int* __restrict__ acci){
  int i=blockIdx.x;
  __shared__ unsigned a[256];
  a[threadIdx.x]=histA[i*256+threadIdx.x];
  __syncthreads();
  if(threadIdx.x==0){
    int np=acci[0];
    int k=min(np, MTOT-np);
    if(k<=0){ acci[2+i]=0x7fffffff; acci[10+i]=0; return; }
    int run=0;
    for(int c=255;c>=0;c--){
      int cb=(int)a[c];
      if(run<k && run+cb>=k){ acci[2+i]=c; acci[10+i]=k-run; return; }
      run+=cb;
    }
    acci[2+i]=0; acci[10+i]=k-run;
  }
}

// fine hist
__global__ void k_histB(const float* __restrict__ lsc, const int* __restrict__ acci,
                        unsigned* __restrict__ histB){
  __shared__ unsigned h[256];
  h[threadIdx.x]=0;
  __syncthreads();
  int i=blockIdx.y;
  int ca=acci[2+i];
  int m=blockIdx.x*blockDim.x+threadIdx.x;
  if(m<MTOT && ca!=0x7fffffff){
    unsigned u=__float_as_uint(lsc[i*MTOT+m]);
    if((int)(u>>24)==ca) atomicAdd(&h[(u>>16)&0xFF],1u);
  }
  __syncthreads();
  unsigned c=h[threadIdx.x];
  if(c) atomicAdd(&histB[i*256+threadIdx.x],c);
}

// fine scan
__global__ void k_scanB(const unsigned* __restrict__ histB, int* __restrict__ acci){
  int i=blockIdx.x;
  __shared__ unsigned a[256];
  a[threadIdx.x]=histB[i*256+threadIdx.x];
  __syncthreads();
  if(threadIdx.x==0){
    int ca=acci[2+i], kres=acci[10+i];
    if(ca==0x7fffffff || kres<=0){ acci[2+i]=0x7fffffff; acci[10+i]=0; return; }
    int run=0;
    for(int f=255;f>=0;f--){
      int cb=(int)a[f];
      if(run<kres && run+cb>=kres){ acci[2+i]=(ca<<8)|f; acci[10+i]=kres-run; return; }
      run+=cb;
    }
    acci[2+i]=(ca<<8); acci[10+i]=kres-run;
  }
}

// select negatives above threshold bin: per-block partial sums (no float atomics);
// boundary-bin members still go to the tiny tie list.
__global__ void k_select(const float* __restrict__ lsc,const float* __restrict__ bcearr,
                         int* __restrict__ acci,float2* __restrict__ part2,
                         int* __restrict__ binlist){
  __shared__ float ss[4]; __shared__ float sc[4];
  int tid=threadIdx.x, lane=tid&63, wid=tid>>6;
  int gid=blockIdx.x*blockDim.x+tid;
  float s=0.f, c=0.f;
  if(gid<NB*MTOT){
    int i=gid/MTOT;
    int bs_=acci[2+i];
    unsigned u=__float_as_uint(lsc[gid]);
    int bin=(int)(u>>16);
    if(bin>bs_){ s=bcearr[gid]; c=1.f; }
    else if(bin==bs_){
      int idx=atomicAdd(&acci[18+i],1);
      if(idx<CAP_LIST){
        binlist[((size_t)i*CAP_LIST+idx)*2  ]=(int)u;
        binlist[((size_t)i*CAP_LIST+idx)*2+1]=gid;
      }
    }
  }
  #pragma unroll
  for(int o=32;o>0;o>>=1){ s+=__shfl_xor(s,o); c+=__shfl_xor(c,o); }
  if(lane==0){ ss[wid]=s; sc[wid]=c; }
  __syncthreads();
  if(tid==0) part2[blockIdx.x]=make_float2(ss[0]+ss[1]+ss[2]+ss[3], sc[0]+sc[1]+sc[2]+sc[3]);
}

// stable tie-resolution (tiny; atomics into dedicated slots accf[5]/acci[1])
__global__ void k_ties(const float* __restrict__ bcearr,int* __restrict__ acci,
                       float* __restrict__ accf,const int* __restrict__ binlist){
  int i=blockIdx.x;
  if(acci[2+i]==0x7fffffff) return;
  int n=min(acci[18+i],CAP_LIST);
  int r=acci[10+i];
  for(int e=threadIdx.x;e<n;e+=blockDim.x){
    unsigned ue=(unsigned)binlist[((size_t)i*CAP_LIST+e)*2];
    int ge=binlist[((size_t)i*CAP_LIST+e)*2+1];
    int rank=0;
    for(int q=0;q<n;q++){
      unsigned uq=(unsigned)binlist[((size_t)i*CAP_LIST+q)*2];
      int gq=binlist[((size_t)i*CAP_LIST+q)*2+1];
      rank += ((uq>ue) || (uq==ue && gq<ge)) ? 1 : 0;
    }
    if(rank<r){
      atomicAdd(&accf[5], bcearr[ge]);
      atomicAdd(&acci[1], 1);
    }
  }
}

// final: reduce k_select partials + combine
__global__ void k_final(const float* __restrict__ accf,const int* __restrict__ acci,
                        const float2* __restrict__ part2,float* __restrict__ out){
  __shared__ float ssum[256]; __shared__ float scnt[256];
  int t=threadIdx.x;
  float s=0.f,c=0.f;
  for(int b=t;b<NBLK_SEL;b+=256){ float2 p=part2[b]; s+=p.x; c+=p.y; }
  ssum[t]=s; scnt[t]=c;
  __syncthreads();
  for(int o=128;o>0;o>>=1){
    if(t<o){ ssum[t]+=ssum[t+o]; scnt[t]+=scnt[t+o]; }
    __syncthreads();
  }
  if(t==0){
    int np=acci[0];
    float npf=(float)np;
    float den2=fmaxf(2.f*npf,1.f);
    float lbox=accf[0]/den2 + accf[1]/den2;
    float lcls=accf[2]/fmaxf(npf,1.f);
    float negsum=ssum[0]+accf[5];
    float negcnt=scnt[0]+(float)acci[1];
    float selc=npf+negcnt;
    float lobj=(accf[3]+negsum)/fmaxf(selc,1.f);
    out[0]=lbox+lcls+lobj;
    out[1]=lbox;
    out[2]=lobj;
    out[3]=lcls;
  }
}

extern "C" void kernel_launch(void* const* d_in, const int* in_sizes, int n_in,
                              void* d_out, int out_size, void* d_ws, size_t ws_size,
                              hipStream_t stream) {
  const float* f0=(const float*)d_in[0];
  const float* f1=(const float*)d_in[1];
  const float* f2=(const float*)d_in[2];
  const float* tg=(const float*)d_in[3];
  const float* priors=(const float*)d_in[4];
  int nt = in_sizes[3]/6;
  if(nt>NT_MAX) nt=NT_MAX;

  char* ws=(char*)d_ws;
  float*    ovr    =(float*)   (ws+O_OVR);
  int*      gix    =(int*)     (ws+O_GIX);
  float*    lsc    =(float*)   (ws+O_LSC);
  float*    bcearr =(float*)   (ws+O_BCE);
  int*      bpi    =(int*)     (ws+O_BPI);
  int*      lj     =(int*)     (ws+O_LJ);
  int*      list   =(int*)     (ws+O_LST);
  float4*   partA  =(float4*)  (ws+O_PA);
  int*      partN  =(int*)     (ws+O_PN);
  float2*   part2  =(float2*)  (ws+O_P2);
  int*      binlist=(int*)     (ws+O_BINL);
  unsigned* histA  =(unsigned*)(ws+O_HA);
  unsigned* histB  =(unsigned*)(ws+O_HB);
  float*    accf   =(float*)   (ws+O_ACC);
  int*      acci   =(int*)     (ws+O_ACCI);
  int*      cnt    =(int*)     (ws+O_CNT);

  // zero hists + accumulators + counters
  hipMemsetAsync(ws+O_HA, 0, (size_t)(O_ZEND-O_HA), stream);

  int ntb=(nt+255)/256;
  k_prep<<<ntb,256,0,stream>>>(tg,nt,list,cnt,lj);
  dim3 gm(GX_MAIN, NB);
  k_match<<<gm,256,0,stream>>>(tg,priors,list,cnt,ovr,gix);
  k_bestprior<<<nt,256,0,stream>>>(tg,priors,nt,bpi);
  k_scatter<<<ntb,256,0,stream>>>(tg,nt,bpi,lj,ovr);
  k_main<<<gm,256,0,stream>>>(f0,f1,f2,tg,priors,ovr,gix,lsc,bcearr,histA,partA,partN);
  k_red<<<1,256,0,stream>>>(partA,partN,accf,acci);
  k_scanA<<<NB,256,0,stream>>>(histA,acci);
  k_histB<<<gm,256,0,stream>>>(lsc,acci,histB);
  k_scanB<<<NB,256,0,stream>>>(histB,acci);
  k_select<<<NBLK_SEL,256,0,stream>>>(lsc,bcearr,acci,part2,binlist);
  k_ties<<<NB,256,0,stream>>>(bcearr,acci,accf,binlist);
  k_final<<<1,256,0,stream>>>(accf,acci,part2,(float*)d_out);
}

// Round 7
// 158.868 us; speedup vs baseline: 3.4587x; 1.1576x over previous
//
#include <hip/hip_runtime.h>
#include <math.h>

#define MTOT 42000
#define NB 8
#define NCLS 80
#define CAP_LIST 4096
#define MAXT 256
#define NT_MAX 2048
#define GX_MAIN 165                 // ceil(42000/256)
#define NBLK_MAIN (GX_MAIN*NB)      // 1320
#define NBLK_SEL 1313               // ceil(336000/256)
#define NCH 32                      // bestprior chunks
#define CS 1313                     // ceil(42000/32)

// ---- workspace byte offsets ----
#define O_OVR 0
#define O_GIX (O_OVR + NB*MTOT*4)
#define O_LSC (O_GIX + NB*MTOT*4)
#define O_BCE (O_LSC + NB*MTOT*4)
#define O_BPI (O_BCE + NB*MTOT*4)
#define O_LJ  (O_BPI + NT_MAX*4)
#define O_LST (O_LJ + NT_MAX*4)
#define O_BPP (O_LST + NB*MAXT*4)        // bestprior u64 partials [NT_MAX][NCH]
#define O_PA  (O_BPP + NT_MAX*NCH*8)     // k_main float4 partials [NBLK_MAIN]
#define O_PN  (O_PA + NBLK_MAIN*16)      // k_main int partials [NBLK_MAIN]
#define O_P2  (O_PN + NBLK_MAIN*4)       // k_select float2 partials [NBLK_SEL]
#define O_BINL (O_P2 + NBLK_SEL*8)
// zeroed region:
#define O_HA  (O_BINL + NB*CAP_LIST*2*4)
#define O_HB  (O_HA + NB*256*4)
#define O_ACC (O_HB + NB*256*4)
#define O_ACCI (O_ACC + 64)
#define O_CNT (O_ACCI + 256)
#define O_ZEND (O_CNT + 64)
// accf: [0]=sum_xy [1]=sum_wh [2]=sum_cls [3]=sum_bce_pos [5]=tie bce sum
// acci: [0]=num_pos [1]=tie negsel cnt [2..9]=bstar16 [10..17]=r [18..25]=tie listn

__device__ __forceinline__ float iou_cxcywh(float acx,float acy,float aw,float ah,
                                            float bcx,float bcy,float bw,float bh){
  float ax0=acx-aw*0.5f, ay0=acy-ah*0.5f, ax1=acx+aw*0.5f, ay1=acy+ah*0.5f;
  float bx0=bcx-bw*0.5f, by0=bcy-bh*0.5f, bx1=bcx+bw*0.5f, by1=bcy+bh*0.5f;
  float tlx=fmaxf(ax0,bx0), tly=fmaxf(ay0,by0);
  float brx=fminf(ax1,bx1), bry=fminf(ay1,by1);
  float wx=fmaxf(brx-tlx,0.f), wy=fmaxf(bry-tly,0.f);
  float inter=wx*wy;
  return inter/(aw*ah+bw*bh-inter+1e-9f);
}

__device__ __forceinline__ float sl1(float x){
  float ax=fabsf(x); return ax<1.f ? 0.5f*ax*ax : ax-0.5f;
}

__device__ __forceinline__ void feat_base(const float* f0,const float* f1,const float* f2,
                                          int i,int m,const float** basep,int* hwp){
  const float* fp; int hw, loc;
  if(m<32000){ fp=f0; hw=6400; loc=m; }
  else if(m<40000){ fp=f1; hw=1600; loc=m-32000; }
  else { fp=f2; hw=400; loc=m-40000; }
  int a=loc/hw, p=loc-a*hw;
  *basep = fp + (size_t)(i*425 + a*85)*(size_t)hw + p;
  *hwp = hw;
}

// parallel per-image target lists
__global__ void k_prep(const float* __restrict__ tg, int nt, int* __restrict__ list,
                       int* __restrict__ cnt, int* __restrict__ lj){
  int t=blockIdx.x*blockDim.x+threadIdx.x;
  if(t>=nt) return;
  int img=(int)tg[t*6];
  int j=0;
  for(int q=0;q<t;q++) if((int)tg[q*6]==img) j++;
  lj[t]=j;
  if(img>=0 && img<NB){
    atomicAdd(&cnt[img],1);
    if(j<MAXT) list[img*MAXT+j]=t;
  }
}

// per (image, prior): max / argmax IoU over that image's targets (first-index tie-break)
__global__ void k_match(const float* __restrict__ tg, const float* __restrict__ priors,
                        const int* __restrict__ list, const int* __restrict__ cnt,
                        float* __restrict__ ovr, int* __restrict__ gix){
  __shared__ float st[MAXT*6];
  __shared__ int   sidx[MAXT];
  int i = blockIdx.y;
  int n = min(cnt[i],MAXT);
  for(int j=threadIdx.x;j<n;j+=blockDim.x){
    int t=list[i*MAXT+j];
    sidx[j]=t;
    #pragma unroll
    for(int q=0;q<6;q++) st[j*6+q]=tg[t*6+q];
  }
  __syncthreads();
  int m = blockIdx.x*blockDim.x + threadIdx.x;
  if(m>=MTOT) return;
  float4 pr = ((const float4*)priors)[m];
  float maxv=-1.0f; int bi=0;
  for(int j=0;j<n;j++){
    float v=iou_cxcywh(st[j*6+2],st[j*6+3],st[j*6+4],st[j*6+5], pr.x,pr.y,pr.z,pr.w);
    if(v>maxv){ maxv=v; bi=sidx[j]; }
  }
  ovr[i*MTOT+m]=maxv; gix[i*MTOT+m]=bi;
}

// bestprior stage A: 2D grid (chunk, target); block-reduce packed (iou<<32)|~m
__global__ void k_bpA(const float* __restrict__ tg, const float* __restrict__ priors,
                      int nt, unsigned long long* __restrict__ part){
  __shared__ unsigned long long s[256];
  int t=blockIdx.y; if(t>=nt) return;
  int c=blockIdx.x;
  float acx=tg[t*6+2],acy=tg[t*6+3],aw=tg[t*6+4],ah=tg[t*6+5];
  int m0=c*CS, m1=min(m0+CS,MTOT);
  float bv=-1.f; int bm=0;
  for(int m=m0+threadIdx.x;m<m1;m+=blockDim.x){
    float4 pr=((const float4*)priors)[m];
    float v=iou_cxcywh(acx,acy,aw,ah,pr.x,pr.y,pr.z,pr.w);
    if(v>bv){ bv=v; bm=m; }   // strict > keeps first (smallest m) within thread
  }
  unsigned long long p = (bv<0.f) ? 0ull
      : (((unsigned long long)__float_as_uint(bv))<<32) | (unsigned)(~bm);
  s[threadIdx.x]=p;
  __syncthreads();
  for(int o=128;o>0;o>>=1){
    if(threadIdx.x<o){ if(s[threadIdx.x+o]>s[threadIdx.x]) s[threadIdx.x]=s[threadIdx.x+o]; }
    __syncthreads();
  }
  if(threadIdx.x==0) part[(size_t)t*NCH+c]=s[0];
}

// bestprior stage B: reduce NCH partials per target -> bpi
__global__ void k_bpB(const unsigned long long* __restrict__ part, int nt,
                      int* __restrict__ bpi){
  __shared__ unsigned long long s[64];
  int t=blockIdx.x; if(t>=nt) return;
  int l=threadIdx.x;
  s[l]=(l<NCH)? part[(size_t)t*NCH+l] : 0ull;
  __syncthreads();
  for(int o=32;o>0;o>>=1){
    if(l<o){ if(s[l+o]>s[l]) s[l]=s[l+o]; }
    __syncthreads();
  }
  if(l==0) bpi[t]=~((unsigned)(s[0]&0xFFFFFFFFull));
}

// forced-prior scatter (parallel last-wins)
__global__ void k_scatter(const float* __restrict__ tg, int nt,
                          const int* __restrict__ bpi, const int* __restrict__ lj,
                          float* __restrict__ ovr){
  int t=blockIdx.x*blockDim.x+threadIdx.x;
  if(t>=nt) return;
  int img=(int)tg[t*6];
  if(img<0||img>=NB) return;
  int myp=bpi[t];
  for(int q=t+1;q<nt;q++)
    if((int)tg[q*6]==img && bpi[q]==myp) return;
  ovr[img*MTOT+myp]=(float)lj[t];
}

// main pass: loss_c/bce + LDS hist + per-thread box losses + wave-cooperative CE.
__global__ void k_main(const float* __restrict__ f0,const float* __restrict__ f1,const float* __restrict__ f2,
                       const float* __restrict__ tg,const float* __restrict__ priors,
                       const float* __restrict__ ovr,const int* __restrict__ gix,
                       float* __restrict__ lsc,float* __restrict__ bcearr,
                       unsigned* __restrict__ histA,
                       float4* __restrict__ partA,int* __restrict__ partN){
  __shared__ unsigned h[256];
  __shared__ float sxy[4],swh[4],sbp[4],sce[4];
  __shared__ int snp[4];
  int tid=threadIdx.x;
  h[tid]=0;
  __syncthreads();
  int i=blockIdx.y;
  int m=blockIdx.x*blockDim.x+tid;
  int lane=tid&63, wid=tid>>6;
  bool valid=(m<MTOT);

  float lxy=0.f,lwh=0.f,bcep=0.f; int npos=0; bool pos=false; int gi=0;
  if(valid){
    int gid=i*MTOT+m;
    const float* base; int hw;
    feat_base(f0,f1,f2,i,m,&base,&hw);
    float ov=ovr[gid]; gi=gix[gid];
    float tc=tg[gi*6+1]+1.0f;
    pos=(ov>=0.5f)&&(tc>0.f);
    float obj=base[(size_t)4*hw];
    float sp=log1pf(expf(-fabsf(obj)));
    float bce=fmaxf(obj,0.f)-(pos?obj:0.f)+sp;
    float lc=pos?0.f:(fmaxf(-obj,0.f)+sp);
    lsc[gid]=lc; bcearr[gid]=bce;
    atomicAdd(&h[__float_as_uint(lc)>>24],1u);
    if(pos){
      npos=1; bcep=bce;
      float4 pr=((const float4*)priors)[m];
      float bx=tg[gi*6+2],by=tg[gi*6+3],bw=tg[gi*6+4],bh=tg[gi*6+5];
      float tx=(bx-pr.x)/pr.z, ty=(by-pr.y)/pr.w;
      float tw=logf(bw/pr.z), th=logf(bh/pr.w);
      lxy=sl1(base[0]-tx)+sl1(base[(size_t)hw]-ty);
      lwh=sl1(base[(size_t)2*hw]-tw)+sl1(base[(size_t)3*hw]-th);
    }
  }

  // wave-cooperative CE
  float wce=0.f;
  unsigned long long mask=__ballot(valid&&pos);
  while(mask){
    int s=__ffsll(mask)-1;
    mask&=mask-1;
    int m_s=__shfl(m,s);
    int gi_s=__shfl(gi,s);
    const float* bs; int hws;
    feat_base(f0,f1,f2,i,m_s,&bs,&hws);
    int label=(int)(tg[gi_s*6+1]+1.0f)-1;
    label=min(NCLS-1,max(0,label));
    float v0=bs[(size_t)(5+lane)*hws];
    float v1=(lane<16)?bs[(size_t)(69+lane)*hws]:-3.0e38f;
    float mx=fmaxf(v0,v1);
    #pragma unroll
    for(int o=32;o>0;o>>=1) mx=fmaxf(mx,__shfl_xor(mx,o));
    float se=expf(v0-mx)+((lane<16)?expf(v1-mx):0.f);
    float xl=((lane==label)?v0:0.f)+((lane<16&&lane+64==label)?v1:0.f);
    #pragma unroll
    for(int o=32;o>0;o>>=1){ se+=__shfl_xor(se,o); xl+=__shfl_xor(xl,o); }
    wce+=logf(se)+mx-xl;
  }

  #pragma unroll
  for(int o=32;o>0;o>>=1){
    lxy+=__shfl_xor(lxy,o); lwh+=__shfl_xor(lwh,o);
    bcep+=__shfl_xor(bcep,o); npos+=__shfl_xor(npos,o);
  }
  if(lane==0){ sxy[wid]=lxy; swh[wid]=lwh; sbp[wid]=bcep; sce[wid]=wce; snp[wid]=npos; }
  __syncthreads();
  unsigned c=h[tid];
  if(c) atomicAdd(&histA[i*256+tid],c);
  if(tid==0){
    float4 pa;
    pa.x=sxy[0]+sxy[1]+sxy[2]+sxy[3];
    pa.y=swh[0]+swh[1]+swh[2]+swh[3];
    pa.z=sce[0]+sce[1]+sce[2]+sce[3];
    pa.w=sbp[0]+sbp[1]+sbp[2]+sbp[3];
    int bid=blockIdx.y*gridDim.x+blockIdx.x;
    partA[bid]=pa;
    partN[bid]=snp[0]+snp[1]+snp[2]+snp[3];
  }
}

// reduce k_main partials -> accf[0..3], acci[0]
__global__ void k_red(const float4* __restrict__ partA,const int* __restrict__ partN,
                      float* __restrict__ accf,int* __restrict__ acci){
  __shared__ float a0[256],a1[256],a2[256],a3[256]; __shared__ int an[256];
  int t=threadIdx.x;
  float x=0,y=0,z=0,w=0; int n=0;
  for(int b=t;b<NBLK_MAIN;b+=256){
    float4 p=partA[b]; x+=p.x; y+=p.y; z+=p.z; w+=p.w; n+=partN[b];
  }
  a0[t]=x; a1[t]=y; a2[t]=z; a3[t]=w; an[t]=n;
  __syncthreads();
  for(int o=128;o>0;o>>=1){
    if(t<o){ a0[t]+=a0[t+o]; a1[t]+=a1[t+o]; a2[t]+=a2[t+o]; a3[t]+=a3[t+o]; an[t]+=an[t+o]; }
    __syncthreads();
  }
  if(t==0){ accf[0]=a0[0]; accf[1]=a1[0]; accf[2]=a2[0]; accf[3]=a3[0]; acci[0]=an[0]; }
}

// coarse scan
__global__ void k_scanA(const unsigned* __restrict__ histA, int* __restrict__ acci){
  int i=blockIdx.x;
  __shared__ unsigned a[256];
  a[threadIdx.x]=histA[i*256+threadIdx.x];
  __syncthreads();
  if(threadIdx.x==0){
    int np=acci[0];
    int k=min(np, MTOT-np);
    if(k<=0){ acci[2+i]=0x7fffffff; acci[10+i]=0; return; }
    int run=0;
    for(int c=255;c>=0;c--){
      int cb=(int)a[c];
      if(run<k && run+cb>=k){ acci[2+i]=c; acci[10+i]=k-run; return; }
      run+=cb;
    }
    acci[2+i]=0; acci[10+i]=k-run;
  }
}

// fine hist
__global__ void k_histB(const float* __restrict__ lsc, const int* __restrict__ acci,
                        unsigned* __restrict__ histB){
  __shared__ unsigned h[256];
  h[threadIdx.x]=0;
  __syncthreads();
  int i=blockIdx.y;
  int ca=acci[2+i];
  int m=blockIdx.x*blockDim.x+threadIdx.x;
  if(m<MTOT && ca!=0x7fffffff){
    unsigned u=__float_as_uint(lsc[i*MTOT+m]);
    if((int)(u>>24)==ca) atomicAdd(&h[(u>>16)&0xFF],1u);
  }
  __syncthreads();
  unsigned c=h[threadIdx.x];
  if(c) atomicAdd(&histB[i*256+threadIdx.x],c);
}

// fine scan
__global__ void k_scanB(const unsigned* __restrict__ histB, int* __restrict__ acci){
  int i=blockIdx.x;
  __shared__ unsigned a[256];
  a[threadIdx.x]=histB[i*256+threadIdx.x];
  __syncthreads();
  if(threadIdx.x==0){
    int ca=acci[2+i], kres=acci[10+i];
    if(ca==0x7fffffff || kres<=0){ acci[2+i]=0x7fffffff; acci[10+i]=0; return; }
    int run=0;
    for(int f=255;f>=0;f--){
      int cb=(int)a[f];
      if(run<kres && run+cb>=kres){ acci[2+i]=(ca<<8)|f; acci[10+i]=kres-run; return; }
      run+=cb;
    }
    acci[2+i]=(ca<<8); acci[10+i]=kres-run;
  }
}

// select negatives above threshold bin: per-block partial sums
__global__ void k_select(const float* __restrict__ lsc,const float* __restrict__ bcearr,
                         int* __restrict__ acci,float2* __restrict__ part2,
                         int* __restrict__ binlist){
  __shared__ float ss[4]; __shared__ float sc[4];
  int tid=threadIdx.x, lane=tid&63, wid=tid>>6;
  int gid=blockIdx.x*blockDim.x+tid;
  float s=0.f, c=0.f;
  if(gid<NB*MTOT){
    int i=gid/MTOT;
    int bs_=acci[2+i];
    unsigned u=__float_as_uint(lsc[gid]);
    int bin=(int)(u>>16);
    if(bin>bs_){ s=bcearr[gid]; c=1.f; }
    else if(bin==bs_){
      int idx=atomicAdd(&acci[18+i],1);
      if(idx<CAP_LIST){
        binlist[((size_t)i*CAP_LIST+idx)*2  ]=(int)u;
        binlist[((size_t)i*CAP_LIST+idx)*2+1]=gid;
      }
    }
  }
  #pragma unroll
  for(int o=32;o>0;o>>=1){ s+=__shfl_xor(s,o); c+=__shfl_xor(c,o); }
  if(lane==0){ ss[wid]=s; sc[wid]=c; }
  __syncthreads();
  if(tid==0) part2[blockIdx.x]=make_float2(ss[0]+ss[1]+ss[2]+ss[3], sc[0]+sc[1]+sc[2]+sc[3]);
}

// stable tie-resolution
__global__ void k_ties(const float* __restrict__ bcearr,int* __restrict__ acci,
                       float* __restrict__ accf,const int* __restrict__ binlist){
  int i=blockIdx.x;
  if(acci[2+i]==0x7fffffff) return;
  int n=min(acci[18+i],CAP_LIST);
  int r=acci[10+i];
  for(int e=threadIdx.x;e<n;e+=blockDim.x){
    unsigned ue=(unsigned)binlist[((size_t)i*CAP_LIST+e)*2];
    int ge=binlist[((size_t)i*CAP_LIST+e)*2+1];
    int rank=0;
    for(int q=0;q<n;q++){
      unsigned uq=(unsigned)binlist[((size_t)i*CAP_LIST+q)*2];
      int gq=binlist[((size_t)i*CAP_LIST+q)*2+1];
      rank += ((uq>ue) || (uq==ue && gq<ge)) ? 1 : 0;
    }
    if(rank<r){
      atomicAdd(&accf[5], bcearr[ge]);
      atomicAdd(&acci[1], 1);
    }
  }
}

// final: reduce k_select partials + combine
__global__ void k_final(const float* __restrict__ accf,const int* __restrict__ acci,
                        const float2* __restrict__ part2,float* __restrict__ out){
  __shared__ float ssum[256]; __shared__ float scnt[256];
  int t=threadIdx.x;
  float s=0.f,c=0.f;
  for(int b=t;b<NBLK_SEL;b+=256){ float2 p=part2[b]; s+=p.x; c+=p.y; }
  ssum[t]=s; scnt[t]=c;
  __syncthreads();
  for(int o=128;o>0;o>>=1){
    if(t<o){ ssum[t]+=ssum[t+o]; scnt[t]+=scnt[t+o]; }
    __syncthreads();
  }
  if(t==0){
    int np=acci[0];
    float npf=(float)np;
    float den2=fmaxf(2.f*npf,1.f);
    float lbox=accf[0]/den2 + accf[1]/den2;
    float lcls=accf[2]/fmaxf(npf,1.f);
    float negsum=ssum[0]+accf[5];
    float negcnt=scnt[0]+(float)acci[1];
    float selc=npf+negcnt;
    float lobj=(accf[3]+negsum)/fmaxf(selc,1.f);
    out[0]=lbox+lcls+lobj;
    out[1]=lbox;
    out[2]=lobj;
    out[3]=lcls;
  }
}

extern "C" void kernel_launch(void* const* d_in, const int* in_sizes, int n_in,
                              void* d_out, int out_size, void* d_ws, size_t ws_size,
                              hipStream_t stream) {
  const float* f0=(const float*)d_in[0];
  const float* f1=(const float*)d_in[1];
  const float* f2=(const float*)d_in[2];
  const float* tg=(const float*)d_in[3];
  const float* priors=(const float*)d_in[4];
  int nt = in_sizes[3]/6;
  if(nt>NT_MAX) nt=NT_MAX;

  char* ws=(char*)d_ws;
  float*    ovr    =(float*)   (ws+O_OVR);
  int*      gix    =(int*)     (ws+O_GIX);
  float*    lsc    =(float*)   (ws+O_LSC);
  float*    bcearr =(float*)   (ws+O_BCE);
  int*      bpi    =(int*)     (ws+O_BPI);
  int*      lj     =(int*)     (ws+O_LJ);
  int*      list   =(int*)     (ws+O_LST);
  unsigned long long* bpp=(unsigned long long*)(ws+O_BPP);
  float4*   partA  =(float4*)  (ws+O_PA);
  int*      partN  =(int*)     (ws+O_PN);
  float2*   part2  =(float2*)  (ws+O_P2);
  int*      binlist=(int*)     (ws+O_BINL);
  unsigned* histA  =(unsigned*)(ws+O_HA);
  unsigned* histB  =(unsigned*)(ws+O_HB);
  float*    accf   =(float*)   (ws+O_ACC);
  int*      acci   =(int*)     (ws+O_ACCI);
  int*      cnt    =(int*)     (ws+O_CNT);

  // zero hists + accumulators + counters
  hipMemsetAsync(ws+O_HA, 0, (size_t)(O_ZEND-O_HA), stream);

  int ntb=(nt+255)/256;
  k_prep<<<ntb,256,0,stream>>>(tg,nt,list,cnt,lj);
  dim3 gm(GX_MAIN, NB);
  k_match<<<gm,256,0,stream>>>(tg,priors,list,cnt,ovr,gix);
  dim3 gbp(NCH, nt);
  k_bpA<<<gbp,256,0,stream>>>(tg,priors,nt,bpp);
  k_bpB<<<nt,64,0,stream>>>(bpp,nt,bpi);
  k_scatter<<<ntb,256,0,stream>>>(tg,nt,bpi,lj,ovr);
  k_main<<<gm,256,0,stream>>>(f0,f1,f2,tg,priors,ovr,gix,lsc,bcearr,histA,partA,partN);
  k_red<<<1,256,0,stream>>>(partA,partN,accf,acci);
  k_scanA<<<NB,256,0,stream>>>(histA,acci);
  k_histB<<<gm,256,0,stream>>>(lsc,acci,histB);
  k_scanB<<<NB,256,0,stream>>>(histB,acci);
  k_select<<<NBLK_SEL,256,0,stream>>>(lsc,bcearr,acci,part2,binlist);
  k_ties<<<NB,256,0,stream>>>(bcearr,acci,accf,binlist);
  k_final<<<1,256,0,stream>>>(accf,acci,part2,(float*)d_out);
}

// Round 8
// 151.479 us; speedup vs baseline: 3.6274x; 1.0488x over previous
//
#include <hip/hip_runtime.h>
#include <math.h>

#define MTOT 42000
#define NB 8
#define NCLS 80
#define CAP_LIST 4096
#define MAXT 256
#define NT_MAX 2048
#define GX_MAIN 165                 // ceil(42000/256)
#define NBLK_MAIN (GX_MAIN*NB)      // 1320
#define NCH 32                      // bestprior chunks
#define CS 1313                     // ceil(42000/32)

// ---- workspace byte offsets ----
#define O_OVR 0
#define O_GIX (O_OVR + NB*MTOT*4)
#define O_LSC (O_GIX + NB*MTOT*4)
#define O_BCE (O_LSC + NB*MTOT*4)
#define O_BPI (O_BCE + NB*MTOT*4)
#define O_LJ  (O_BPI + NT_MAX*4)
#define O_LST (O_LJ + NT_MAX*4)
#define O_BPP (O_LST + NB*MAXT*4)        // bestprior u64 partials [NT_MAX][NCH]
#define O_PA  (O_BPP + NT_MAX*NCH*8)     // k_main float4 partials [NBLK_MAIN]
#define O_PN  (O_PA + NBLK_MAIN*16)      // k_main int partials [NBLK_MAIN]
#define O_P2  (O_PN + NBLK_MAIN*4)       // k_select float2 partials [NBLK_MAIN]
#define O_BINL (O_P2 + NBLK_MAIN*8)
#define O_CNT (O_BINL + NB*CAP_LIST*2*4) // cnt (NOT zeroed; plain-stored by k_init)
// kernel-zeroed region [O_HA, O_ZEND):
#define O_HA  (((O_CNT + NB*4 + 255)/256)*256)
#define O_HB  (O_HA + NB*256*4)
#define O_ACC (O_HB + NB*256*4)
#define O_ACCI (O_ACC + 64)
#define O_ZEND (O_ACCI + 256)
#define ZWORDS ((O_ZEND - O_HA)/4)
#define ZBLK ((ZWORDS + 255)/256)
// accf: [0]=sum_xy [1]=sum_wh [2]=sum_cls [3]=sum_bce_pos [5]=tie bce sum
// acci: [0]=num_pos [1]=tie negsel cnt [2..9]=coarse bin ca [10..17]=kres [18..25]=tie listn

__device__ __forceinline__ float iou_cxcywh(float acx,float acy,float aw,float ah,
                                            float bcx,float bcy,float bw,float bh){
  float ax0=acx-aw*0.5f, ay0=acy-ah*0.5f, ax1=acx+aw*0.5f, ay1=acy+ah*0.5f;
  float bx0=bcx-bw*0.5f, by0=bcy-bh*0.5f, bx1=bcx+bw*0.5f, by1=bcy+bh*0.5f;
  float tlx=fmaxf(ax0,bx0), tly=fmaxf(ay0,by0);
  float brx=fminf(ax1,bx1), bry=fminf(ay1,by1);
  float wx=fmaxf(brx-tlx,0.f), wy=fmaxf(bry-tly,0.f);
  float inter=wx*wy;
  return inter/(aw*ah+bw*bh-inter+1e-9f);
}

__device__ __forceinline__ float sl1(float x){
  float ax=fabsf(x); return ax<1.f ? 0.5f*ax*ax : ax-0.5f;
}

__device__ __forceinline__ void feat_base(const float* f0,const float* f1,const float* f2,
                                          int i,int m,const float** basep,int* hwp){
  const float* fp; int hw, loc;
  if(m<32000){ fp=f0; hw=6400; loc=m; }
  else if(m<40000){ fp=f1; hw=1600; loc=m-32000; }
  else { fp=f2; hw=400; loc=m-40000; }
  int a=loc/hw, p=loc-a*hw;
  *basep = fp + (size_t)(i*425 + a*85)*(size_t)hw + p;
  *hwp = hw;
}

// fused: zero hist/acc region (blocks 0..ZBLK-1) + per-image target prep (rest)
__global__ void k_init(const float* __restrict__ tg, int nt, int* __restrict__ list,
                       int* __restrict__ cnt, int* __restrict__ lj,
                       unsigned* __restrict__ zbase){
  int bx=blockIdx.x, tid=threadIdx.x;
  if(bx<ZBLK){
    int w=bx*256+tid;
    if(w<ZWORDS) zbase[w]=0u;
    return;
  }
  if(bx==ZBLK && tid<NB){      // plain-store counts (no atomics, no pre-zero needed)
    int c=0;
    for(int q=0;q<nt;q++) if((int)tg[q*6]==tid) c++;
    cnt[tid]=c;
  }
  int t=(bx-ZBLK)*256+tid;
  if(t>=nt) return;
  int img=(int)tg[t*6];
  int j=0;
  for(int q=0;q<t;q++) if((int)tg[q*6]==img) j++;
  lj[t]=j;
  if(img>=0 && img<NB && j<MAXT) list[img*MAXT+j]=t;
}

// per (image, prior): max / argmax IoU over that image's targets (first-index tie-break)
__global__ void k_match(const float* __restrict__ tg, const float* __restrict__ priors,
                        const int* __restrict__ list, const int* __restrict__ cnt,
                        float* __restrict__ ovr, int* __restrict__ gix){
  __shared__ float st[MAXT*6];
  __shared__ int   sidx[MAXT];
  int i = blockIdx.y;
  int n = min(cnt[i],MAXT);
  for(int j=threadIdx.x;j<n;j+=blockDim.x){
    int t=list[i*MAXT+j];
    sidx[j]=t;
    #pragma unroll
    for(int q=0;q<6;q++) st[j*6+q]=tg[t*6+q];
  }
  __syncthreads();
  int m = blockIdx.x*blockDim.x + threadIdx.x;
  if(m>=MTOT) return;
  float4 pr = ((const float4*)priors)[m];
  float maxv=-1.0f; int bi=0;
  for(int j=0;j<n;j++){
    float v=iou_cxcywh(st[j*6+2],st[j*6+3],st[j*6+4],st[j*6+5], pr.x,pr.y,pr.z,pr.w);
    if(v>maxv){ maxv=v; bi=sidx[j]; }
  }
  ovr[i*MTOT+m]=maxv; gix[i*MTOT+m]=bi;
}

// bestprior stage A: 2D grid (chunk, target); block-reduce packed (iou<<32)|~m
__global__ void k_bpA(const float* __restrict__ tg, const float* __restrict__ priors,
                      int nt, unsigned long long* __restrict__ part){
  __shared__ unsigned long long s[256];
  int t=blockIdx.y; if(t>=nt) return;
  int c=blockIdx.x;
  float acx=tg[t*6+2],acy=tg[t*6+3],aw=tg[t*6+4],ah=tg[t*6+5];
  int m0=c*CS, m1=min(m0+CS,MTOT);
  float bv=-1.f; int bm=0;
  for(int m=m0+threadIdx.x;m<m1;m+=blockDim.x){
    float4 pr=((const float4*)priors)[m];
    float v=iou_cxcywh(acx,acy,aw,ah,pr.x,pr.y,pr.z,pr.w);
    if(v>bv){ bv=v; bm=m; }   // strict > keeps first (smallest m) within thread
  }
  unsigned long long p = (bv<0.f) ? 0ull
      : (((unsigned long long)__float_as_uint(bv))<<32) | (unsigned)(~bm);
  s[threadIdx.x]=p;
  __syncthreads();
  for(int o=128;o>0;o>>=1){
    if(threadIdx.x<o){ if(s[threadIdx.x+o]>s[threadIdx.x]) s[threadIdx.x]=s[threadIdx.x+o]; }
    __syncthreads();
  }
  if(threadIdx.x==0) part[(size_t)t*NCH+c]=s[0];
}

// bestprior stage B: reduce NCH partials per target -> bpi
__global__ void k_bpB(const unsigned long long* __restrict__ part, int nt,
                      int* __restrict__ bpi){
  __shared__ unsigned long long s[64];
  int t=blockIdx.x; if(t>=nt) return;
  int l=threadIdx.x;
  s[l]=(l<NCH)? part[(size_t)t*NCH+l] : 0ull;
  __syncthreads();
  for(int o=32;o>0;o>>=1){
    if(l<o){ if(s[l+o]>s[l]) s[l]=s[l+o]; }
    __syncthreads();
  }
  if(l==0) bpi[t]=~((unsigned)(s[0]&0xFFFFFFFFull));
}

// forced-prior scatter (parallel last-wins)
__global__ void k_scatter(const float* __restrict__ tg, int nt,
                          const int* __restrict__ bpi, const int* __restrict__ lj,
                          float* __restrict__ ovr){
  int t=blockIdx.x*blockDim.x+threadIdx.x;
  if(t>=nt) return;
  int img=(int)tg[t*6];
  if(img<0||img>=NB) return;
  int myp=bpi[t];
  for(int q=t+1;q<nt;q++)
    if((int)tg[q*6]==img && bpi[q]==myp) return;
  ovr[img*MTOT+myp]=(float)lj[t];
}

// main pass: loss_c/bce + LDS hist + per-thread box losses + wave-cooperative CE.
__global__ void k_main(const float* __restrict__ f0,const float* __restrict__ f1,const float* __restrict__ f2,
                       const float* __restrict__ tg,const float* __restrict__ priors,
                       const float* __restrict__ ovr,const int* __restrict__ gix,
                       float* __restrict__ lsc,float* __restrict__ bcearr,
                       unsigned* __restrict__ histA,
                       float4* __restrict__ partA,int* __restrict__ partN){
  __shared__ unsigned h[256];
  __shared__ float sxy[4],swh[4],sbp[4],sce[4];
  __shared__ int snp[4];
  int tid=threadIdx.x;
  h[tid]=0;
  __syncthreads();
  int i=blockIdx.y;
  int m=blockIdx.x*blockDim.x+tid;
  int lane=tid&63, wid=tid>>6;
  bool valid=(m<MTOT);

  float lxy=0.f,lwh=0.f,bcep=0.f; int npos=0; bool pos=false; int gi=0;
  if(valid){
    int gid=i*MTOT+m;
    const float* base; int hw;
    feat_base(f0,f1,f2,i,m,&base,&hw);
    float ov=ovr[gid]; gi=gix[gid];
    float tc=tg[gi*6+1]+1.0f;
    pos=(ov>=0.5f)&&(tc>0.f);
    float obj=base[(size_t)4*hw];
    float sp=log1pf(expf(-fabsf(obj)));
    float bce=fmaxf(obj,0.f)-(pos?obj:0.f)+sp;
    float lc=pos?0.f:(fmaxf(-obj,0.f)+sp);
    lsc[gid]=lc; bcearr[gid]=bce;
    atomicAdd(&h[__float_as_uint(lc)>>24],1u);
    if(pos){
      npos=1; bcep=bce;
      float4 pr=((const float4*)priors)[m];
      float bx=tg[gi*6+2],by=tg[gi*6+3],bw=tg[gi*6+4],bh=tg[gi*6+5];
      float tx=(bx-pr.x)/pr.z, ty=(by-pr.y)/pr.w;
      float tw=logf(bw/pr.z), th=logf(bh/pr.w);
      lxy=sl1(base[0]-tx)+sl1(base[(size_t)hw]-ty);
      lwh=sl1(base[(size_t)2*hw]-tw)+sl1(base[(size_t)3*hw]-th);
    }
  }

  // wave-cooperative CE
  float wce=0.f;
  unsigned long long mask=__ballot(valid&&pos);
  while(mask){
    int s=__ffsll(mask)-1;
    mask&=mask-1;
    int m_s=__shfl(m,s);
    int gi_s=__shfl(gi,s);
    const float* bs; int hws;
    feat_base(f0,f1,f2,i,m_s,&bs,&hws);
    int label=(int)(tg[gi_s*6+1]+1.0f)-1;
    label=min(NCLS-1,max(0,label));
    float v0=bs[(size_t)(5+lane)*hws];
    float v1=(lane<16)?bs[(size_t)(69+lane)*hws]:-3.0e38f;
    float mx=fmaxf(v0,v1);
    #pragma unroll
    for(int o=32;o>0;o>>=1) mx=fmaxf(mx,__shfl_xor(mx,o));
    float se=expf(v0-mx)+((lane<16)?expf(v1-mx):0.f);
    float xl=((lane==label)?v0:0.f)+((lane<16&&lane+64==label)?v1:0.f);
    #pragma unroll
    for(int o=32;o>0;o>>=1){ se+=__shfl_xor(se,o); xl+=__shfl_xor(xl,o); }
    wce+=logf(se)+mx-xl;
  }

  #pragma unroll
  for(int o=32;o>0;o>>=1){
    lxy+=__shfl_xor(lxy,o); lwh+=__shfl_xor(lwh,o);
    bcep+=__shfl_xor(bcep,o); npos+=__shfl_xor(npos,o);
  }
  if(lane==0){ sxy[wid]=lxy; swh[wid]=lwh; sbp[wid]=bcep; sce[wid]=wce; snp[wid]=npos; }
  __syncthreads();
  unsigned c=h[tid];
  if(c) atomicAdd(&histA[i*256+tid],c);
  if(tid==0){
    float4 pa;
    pa.x=sxy[0]+sxy[1]+sxy[2]+sxy[3];
    pa.y=swh[0]+swh[1]+swh[2]+swh[3];
    pa.z=sce[0]+sce[1]+sce[2]+sce[3];
    pa.w=sbp[0]+sbp[1]+sbp[2]+sbp[3];
    int bid=blockIdx.y*gridDim.x+blockIdx.x;
    partA[bid]=pa;
    partN[bid]=snp[0]+snp[1]+snp[2]+snp[3];
  }
}

// fused: reduce k_main partials (block 0 writes accf/acci[0]; all blocks get np)
// + coarse scanA for image i=blockIdx.x
__global__ void k_redscanA(const float4* __restrict__ partA,const int* __restrict__ partN,
                           const unsigned* __restrict__ histA,
                           float* __restrict__ accf,int* __restrict__ acci){
  __shared__ int an[256];
  __shared__ float a0[256],a1[256],a2[256],a3[256];
  __shared__ unsigned a[256];
  int t=threadIdx.x, i=blockIdx.x;
  bool lead=(i==0);
  int n=0; float x=0,y=0,z=0,w=0;
  for(int b=t;b<NBLK_MAIN;b+=256){
    n+=partN[b];
    if(lead){ float4 p=partA[b]; x+=p.x; y+=p.y; z+=p.z; w+=p.w; }
  }
  an[t]=n;
  if(lead){ a0[t]=x; a1[t]=y; a2[t]=z; a3[t]=w; }
  __syncthreads();
  for(int o=128;o>0;o>>=1){
    if(t<o){
      an[t]+=an[t+o];
      if(lead){ a0[t]+=a0[t+o]; a1[t]+=a1[t+o]; a2[t]+=a2[t+o]; a3[t]+=a3[t+o]; }
    }
    __syncthreads();
  }
  int np=an[0];
  if(lead && t==0){ accf[0]=a0[0]; accf[1]=a1[0]; accf[2]=a2[0]; accf[3]=a3[0]; acci[0]=np; }
  a[t]=histA[i*256+t];
  __syncthreads();
  if(t==0){
    int k=min(np, MTOT-np);
    if(k<=0){ acci[2+i]=0x7fffffff; acci[10+i]=0; return; }
    int run=0;
    for(int c=255;c>=0;c--){
      int cb=(int)a[c];
      if(run<k && run+cb>=k){ acci[2+i]=c; acci[10+i]=k-run; return; }
      run+=cb;
    }
    acci[2+i]=0; acci[10+i]=k-run;
  }
}

// fine hist
__global__ void k_histB(const float* __restrict__ lsc, const int* __restrict__ acci,
                        unsigned* __restrict__ histB){
  __shared__ unsigned h[256];
  h[threadIdx.x]=0;
  __syncthreads();
  int i=blockIdx.y;
  int ca=acci[2+i];
  int m=blockIdx.x*blockDim.x+threadIdx.x;
  if(m<MTOT && ca!=0x7fffffff){
    unsigned u=__float_as_uint(lsc[i*MTOT+m]);
    if((int)(u>>24)==ca) atomicAdd(&h[(u>>16)&0xFF],1u);
  }
  __syncthreads();
  unsigned c=h[threadIdx.x];
  if(c) atomicAdd(&histB[i*256+threadIdx.x],c);
}

// inline fine-scan helper: returns 16-bit boundary bin bs and residual r
__device__ __forceinline__ void fine_scan(const unsigned* hb,int ca,int kres,int* bs_out,int* r_out){
  if(ca==0x7fffffff){ *bs_out=0x7fffffff; *r_out=0; return; }
  int run=0, bs=-1, r=0;
  for(int f=255;f>=0;f--){
    int cb=(int)hb[f];
    if(run<kres && run+cb>=kres){ bs=(ca<<8)|f; r=kres-run; break; }
    run+=cb;
  }
  if(bs<0){ bs=(ca<<8); r=kres-run; }
  *bs_out=bs; *r_out=r;
}

// select negatives above 16-bit threshold bin (computed in-block from histB):
// per-block partial sums; boundary-bin members go to the tie list. 2D grid (GX_MAIN, NB).
__global__ void k_select(const float* __restrict__ lsc,const float* __restrict__ bcearr,
                         const unsigned* __restrict__ histB,
                         int* __restrict__ acci,float2* __restrict__ part2,
                         int* __restrict__ binlist){
  __shared__ unsigned hb[256];
  __shared__ int sbs;
  __shared__ float ss[4]; __shared__ float sc[4];
  int tid=threadIdx.x, lane=tid&63, wid=tid>>6;
  int i=blockIdx.y;
  int ca=acci[2+i], kres=acci[10+i];
  hb[tid]=(ca==0x7fffffff)?0u:histB[i*256+tid];
  __syncthreads();
  if(tid==0){ int bs,r; fine_scan(hb,ca,kres,&bs,&r); sbs=bs; }
  __syncthreads();
  int bs_=sbs;
  int m=blockIdx.x*blockDim.x+tid;
  float s=0.f, c=0.f;
  if(m<MTOT){
    int gid=i*MTOT+m;
    unsigned u=__float_as_uint(lsc[gid]);
    int bin=(int)(u>>16);
    if(bin>bs_){ s=bcearr[gid]; c=1.f; }
    else if(bin==bs_){
      int idx=atomicAdd(&acci[18+i],1);
      if(idx<CAP_LIST){
        binlist[((size_t)i*CAP_LIST+idx)*2  ]=(int)u;
        binlist[((size_t)i*CAP_LIST+idx)*2+1]=gid;
      }
    }
  }
  #pragma unroll
  for(int o=32;o>0;o>>=1){ s+=__shfl_xor(s,o); c+=__shfl_xor(c,o); }
  if(lane==0){ ss[wid]=s; sc[wid]=c; }
  __syncthreads();
  if(tid==0) part2[blockIdx.y*gridDim.x+blockIdx.x]=make_float2(ss[0]+ss[1]+ss[2]+ss[3], sc[0]+sc[1]+sc[2]+sc[3]);
}

// stable tie-resolution (recomputes bs/r locally from histB)
__global__ void k_ties(const float* __restrict__ bcearr,int* __restrict__ acci,
                       float* __restrict__ accf,const int* __restrict__ binlist,
                       const unsigned* __restrict__ histB){
  __shared__ unsigned hb[256];
  __shared__ int sbs, sr;
  int i=blockIdx.x, tid=threadIdx.x;
  int ca=acci[2+i], kres=acci[10+i];
  hb[tid]=(ca==0x7fffffff)?0u:histB[i*256+tid];
  __syncthreads();
  if(tid==0){ int bs,r; fine_scan(hb,ca,kres,&bs,&r); sbs=bs; sr=r; }
  __syncthreads();
  if(sbs==0x7fffffff) return;
  int n=min(acci[18+i],CAP_LIST);
  int r=sr;
  for(int e=tid;e<n;e+=blockDim.x){
    unsigned ue=(unsigned)binlist[((size_t)i*CAP_LIST+e)*2];
    int ge=binlist[((size_t)i*CAP_LIST+e)*2+1];
    int rank=0;
    for(int q=0;q<n;q++){
      unsigned uq=(unsigned)binlist[((size_t)i*CAP_LIST+q)*2];
      int gq=binlist[((size_t)i*CAP_LIST+q)*2+1];
      rank += ((uq>ue) || (uq==ue && gq<ge)) ? 1 : 0;
    }
    if(rank<r){
      atomicAdd(&accf[5], bcearr[ge]);
      atomicAdd(&acci[1], 1);
    }
  }
}

// final: reduce k_select partials + combine
__global__ void k_final(const float* __restrict__ accf,const int* __restrict__ acci,
                        const float2* __restrict__ part2,float* __restrict__ out){
  __shared__ float ssum[256]; __shared__ float scnt[256];
  int t=threadIdx.x;
  float s=0.f,c=0.f;
  for(int b=t;b<NBLK_MAIN;b+=256){ float2 p=part2[b]; s+=p.x; c+=p.y; }
  ssum[t]=s; scnt[t]=c;
  __syncthreads();
  for(int o=128;o>0;o>>=1){
    if(t<o){ ssum[t]+=ssum[t+o]; scnt[t]+=scnt[t+o]; }
    __syncthreads();
  }
  if(t==0){
    int np=acci[0];
    float npf=(float)np;
    float den2=fmaxf(2.f*npf,1.f);
    float lbox=accf[0]/den2 + accf[1]/den2;
    float lcls=accf[2]/fmaxf(npf,1.f);
    float negsum=ssum[0]+accf[5];
    float negcnt=scnt[0]+(float)acci[1];
    float selc=npf+negcnt;
    float lobj=(accf[3]+negsum)/fmaxf(selc,1.f);
    out[0]=lbox+lcls+lobj;
    out[1]=lbox;
    out[2]=lobj;
    out[3]=lcls;
  }
}

extern "C" void kernel_launch(void* const* d_in, const int* in_sizes, int n_in,
                              void* d_out, int out_size, void* d_ws, size_t ws_size,
                              hipStream_t stream) {
  const float* f0=(const float*)d_in[0];
  const float* f1=(const float*)d_in[1];
  const float* f2=(const float*)d_in[2];
  const float* tg=(const float*)d_in[3];
  const float* priors=(const float*)d_in[4];
  int nt = in_sizes[3]/6;
  if(nt>NT_MAX) nt=NT_MAX;

  char* ws=(char*)d_ws;
  float*    ovr    =(float*)   (ws+O_OVR);
  int*      gix    =(int*)     (ws+O_GIX);
  float*    lsc    =(float*)   (ws+O_LSC);
  float*    bcearr =(float*)   (ws+O_BCE);
  int*      bpi    =(int*)     (ws+O_BPI);
  int*      lj     =(int*)     (ws+O_LJ);
  int*      list   =(int*)     (ws+O_LST);
  unsigned long long* bpp=(unsigned long long*)(ws+O_BPP);
  float4*   partA  =(float4*)  (ws+O_PA);
  int*      partN  =(int*)     (ws+O_PN);
  float2*   part2  =(float2*)  (ws+O_P2);
  int*      binlist=(int*)     (ws+O_BINL);
  int*      cnt    =(int*)     (ws+O_CNT);
  unsigned* histA  =(unsigned*)(ws+O_HA);
  unsigned* histB  =(unsigned*)(ws+O_HB);
  float*    accf   =(float*)   (ws+O_ACC);
  int*      acci   =(int*)     (ws+O_ACCI);
  unsigned* zbase  =(unsigned*)(ws+O_HA);

  int ntb=(nt+255)/256;
  k_init<<<ZBLK+ntb,256,0,stream>>>(tg,nt,list,cnt,lj,zbase);
  dim3 gm(GX_MAIN, NB);
  k_match<<<gm,256,0,stream>>>(tg,priors,list,cnt,ovr,gix);
  dim3 gbp(NCH, nt);
  k_bpA<<<gbp,256,0,stream>>>(tg,priors,nt,bpp);
  k_bpB<<<nt,64,0,stream>>>(bpp,nt,bpi);
  k_scatter<<<ntb,256,0,stream>>>(tg,nt,bpi,lj,ovr);
  k_main<<<gm,256,0,stream>>>(f0,f1,f2,tg,priors,ovr,gix,lsc,bcearr,histA,partA,partN);
  k_redscanA<<<NB,256,0,stream>>>(partA,partN,histA,accf,acci);
  k_histB<<<gm,256,0,stream>>>(lsc,acci,histB);
  k_select<<<gm,256,0,stream>>>(lsc,bcearr,histB,acci,part2,binlist);
  k_ties<<<NB,256,0,stream>>>(bcearr,acci,accf,binlist,histB);
  k_final<<<1,256,0,stream>>>(accf,acci,part2,(float*)d_out);
}